// Round 14
// baseline (873.055 us; speedup 1.0000x reference)
//
#include <hip/hip_runtime.h>
#include <hip/hip_bf16.h>

// MLA transformer block, bf16 MFMA implementation.
// R14: revert to R11 GEMM config (sb1 everywhere; sb2 regressed). NEW: gemm_gu —
//      fused gate+up GEMM (shared A staged once, dual accumulators, silu in
//      epilogue; 34 KB/MFLOP LDS traffic vs 45.7; kills gbuf gate round-trip).
//      WuT uses the dead qd/q arena as a second weight slot. Attention unchanged.

using bf16x8 = __attribute__((ext_vector_type(8))) short;
using f32x4  = __attribute__((ext_vector_type(4))) float;

#define GLOBAL_AS __attribute__((address_space(1)))
#define LDS_AS    __attribute__((address_space(3)))
#define MFMA16(a, b, c) __builtin_amdgcn_mfma_f32_16x16x32_bf16((a), (b), (c), 0, 0, 0)

static constexpr int Sc = 2048;

__device__ __forceinline__ void gload16(const void* g, void* l) {
  __builtin_amdgcn_global_load_lds((const GLOBAL_AS unsigned int*)g,
                                   (LDS_AS unsigned int*)l, 16, 0, 0);
}
__device__ __forceinline__ float bf2f(unsigned short u) {
  union { float f; unsigned int i; } x; x.i = ((unsigned int)u) << 16; return x.f;
}
__device__ __forceinline__ unsigned short f2bf(float f) {
  union { float f; unsigned int i; } x; x.f = f;
  unsigned int i = x.i;
  return (unsigned short)((i + 0x7fffu + ((i >> 16) & 1u)) >> 16);
}
__device__ __forceinline__ int swz4(int r) { return ((r >> 2) & 3) ^ (r & 3); }

// ---------------- diagnostic fill (ws too small beacon) ----------------
__global__ void fill_k(float* out, float v, int n) {
  int i = blockIdx.x * 256 + threadIdx.x;
  if (i < n) out[i] = v;
}

// -------- weight transpose+cast: W[K][N] f32 -> WT[N][K] bf16, 64n x 64k tiles ------
__global__ __launch_bounds__(256) void wtrans(const float* __restrict__ W,
                                              unsigned short* __restrict__ WT,
                                              int K, int N) {
  __shared__ float t[64][65];
  const int n0 = blockIdx.x * 64, k0 = blockIdx.y * 64;
  const int tx = threadIdx.x & 15, ty = threadIdx.x >> 4;  // tx: n-gran, ty: k row
#pragma unroll
  for (int i = 0; i < 4; ++i) {
    int k = k0 + ty + i * 16;
    const float4 v = *(const float4*)(W + (size_t)k * N + n0 + tx * 4);
    t[ty + i * 16][tx * 4 + 0] = v.x;
    t[ty + i * 16][tx * 4 + 1] = v.y;
    t[ty + i * 16][tx * 4 + 2] = v.z;
    t[ty + i * 16][tx * 4 + 3] = v.w;
  }
  __syncthreads();
  const int kx = threadIdx.x & 7, ny = threadIdx.x >> 3;  // kx: k-octet, ny 0..31
#pragma unroll
  for (int i = 0; i < 2; ++i) {
    int nl = ny + i * 32;
    unsigned short u[8];
#pragma unroll
    for (int j = 0; j < 8; ++j) u[j] = f2bf(t[kx * 8 + j][nl]);
    *(uint4*)(WT + (size_t)(n0 + nl) * K + k0 + kx * 8) = *(uint4*)u;
  }
}

// ---------------- rope tables ----------------
__global__ void rope_tab(float* __restrict__ cosT, float* __restrict__ sinT) {
  int i = blockIdx.x * 256 + threadIdx.x;
  if (i >= Sc * 32) return;
  int s = i >> 5, j = i & 31;
  float inv = powf(10000.0f, -(float)j / 32.0f);
  float a = (float)s * inv;
  cosT[i] = cosf(a);
  sinT[i] = sinf(a);
}

// ---------------- rmsnorm (f32 in, bf16 out) ----------------
__global__ __launch_bounds__(256) void rmsnorm_k(const float* __restrict__ in,
                                                 const float* __restrict__ w,
                                                 unsigned short* __restrict__ out,
                                                 int D, int istride, int ostride) {
  const int row = blockIdx.x;
  const float* x = in + (size_t)row * istride;
  float ss = 0.f;
  for (int c = threadIdx.x * 4; c < D; c += 1024) {
    const float4 v = *(const float4*)(x + c);
    ss += v.x * v.x + v.y * v.y + v.z * v.z + v.w * v.w;
  }
#pragma unroll
  for (int off = 1; off < 64; off <<= 1) ss += __shfl_xor(ss, off);
  __shared__ float part[4];
  if ((threadIdx.x & 63) == 0) part[threadIdx.x >> 6] = ss;
  __syncthreads();
  float tot = part[0] + part[1] + part[2] + part[3];
  float r = rsqrtf(tot / (float)D + 1e-6f);
  for (int c = threadIdx.x * 4; c < D; c += 1024) {
    const float4 v = *(const float4*)(x + c);
    ushort4 o;
    o.x = f2bf(v.x * r * w[c + 0]);
    o.y = f2bf(v.y * r * w[c + 1]);
    o.z = f2bf(v.z * r * w[c + 2]);
    o.w = f2bf(v.w * r * w[c + 3]);
    *(ushort4*)(out + (size_t)row * ostride + c) = o;
  }
}

enum { EPI_BF16 = 0, EPI_F32 = 1, EPI_ADDF32 = 2, EPI_SILU = 3 };

// ===== gemm_sb1: 128x128, BK=64, 4 waves, SINGLE-buffer LDS (32 KB) — R11 split ====
template <int EPI>
__global__ __launch_bounds__(256) void gemm_sb1(const unsigned short* __restrict__ A,
                                                const unsigned short* __restrict__ BT,
                                                void* __restrict__ Cp,
                                                const float* __restrict__ resid,
                                                const unsigned short* __restrict__ other,
                                                int M, int N, int K) {
  __shared__ unsigned short ldsA[128 * 64];
  __shared__ unsigned short ldsB[128 * 64];
  const int tid = threadIdx.x;
  const int w = tid >> 6, lane = tid & 63;
  const int rl = lane & 15, gh = lane >> 4;
  const int wm = (w >> 1) * 64, wn = (w & 1) * 64;

  const int nwg = gridDim.x;
  const int orig = blockIdx.x;
  const int qq = nwg >> 3, rr = nwg & 7;
  const int xcd = orig & 7, lidx = orig >> 3;
  const int fswz = (xcd < rr ? xcd * (qq + 1) : rr * (qq + 1) + (xcd - rr) * qq) + lidx;
  const int MT = M >> 7;
  const int m0 = (fswz % MT) * 128;
  const int n0 = (fswz / MT) * 128;

  const unsigned short* sA[4];
  const unsigned short* sB[4];
#pragma unroll
  for (int i = 0; i < 4; ++i) {
    int G = i * 256 + tid, r = G >> 3, sl = (G & 7) ^ (r & 7);
    sA[i] = A + (size_t)(m0 + r) * K + sl * 8;
    sB[i] = BT + (size_t)(n0 + r) * K + sl * 8;
  }
  auto STAGE = [&](int kt) {
    const int ko = kt * 64;
#pragma unroll
    for (int i = 0; i < 4; ++i) {
      gload16(sA[i] + ko, &ldsA[(i * 256 + w * 64) * 8]);
      gload16(sB[i] + ko, &ldsB[(i * 256 + w * 64) * 8]);
    }
  };

  int aoff[4], boff[4];
#pragma unroll
  for (int i = 0; i < 4; ++i) {
    aoff[i] = (wm + i * 16 + rl) * 64;
    boff[i] = (wn + i * 16 + rl) * 64;
  }

  f32x4 acc[4][4] = {};
  const int nk = K >> 6;

  STAGE(0);
  asm volatile("s_waitcnt vmcnt(0)" ::: "memory");
  __builtin_amdgcn_s_barrier();

  for (int kt = 0; kt < nk; ++kt) {
    bf16x8 a[4][2], b[4][2];
#pragma unroll
    for (int i = 0; i < 4; ++i)
#pragma unroll
      for (int ks = 0; ks < 2; ++ks) {
        const int ra = wm + i * 16 + rl;
        a[i][ks] = *(const bf16x8*)&ldsA[aoff[i] + ((((ks << 2) + gh)) ^ (ra & 7)) * 8];
        const int rb = wn + i * 16 + rl;
        b[i][ks] = *(const bf16x8*)&ldsB[boff[i] + ((((ks << 2) + gh)) ^ (rb & 7)) * 8];
      }
    asm volatile("s_waitcnt lgkmcnt(0)" ::: "memory");
    __builtin_amdgcn_sched_barrier(0);
    __builtin_amdgcn_s_setprio(1);
#pragma unroll
    for (int i = 0; i < 4; ++i)
#pragma unroll
      for (int j = 0; j < 4; ++j) acc[i][j] = MFMA16(a[i][0], b[j][0], acc[i][j]);
    __builtin_amdgcn_s_setprio(0);
    __builtin_amdgcn_sched_barrier(0);
    __builtin_amdgcn_s_barrier();
    STAGE((kt + 1 < nk) ? kt + 1 : nk - 1);
    __builtin_amdgcn_sched_barrier(0);
    __builtin_amdgcn_s_setprio(1);
#pragma unroll
    for (int i = 0; i < 4; ++i)
#pragma unroll
      for (int j = 0; j < 4; ++j) acc[i][j] = MFMA16(a[i][1], b[j][1], acc[i][j]);
    __builtin_amdgcn_s_setprio(0);
    __builtin_amdgcn_sched_barrier(0);
    asm volatile("s_waitcnt vmcnt(0)" ::: "memory");
    __builtin_amdgcn_s_barrier();
  }

#pragma unroll
  for (int i = 0; i < 4; ++i) {
#pragma unroll
    for (int j = 0; j < 4; ++j) {
#pragma unroll
      for (int rg = 0; rg < 4; ++rg) {
        const int row = m0 + wm + i * 16 + gh * 4 + rg;
        const int col = n0 + wn + j * 16 + rl;
        const size_t idx = (size_t)row * N + col;
        const float v = acc[i][j][rg];
        if constexpr (EPI == EPI_BF16) {
          ((unsigned short*)Cp)[idx] = f2bf(v);
        } else if constexpr (EPI == EPI_F32) {
          ((float*)Cp)[idx] = v;
        } else if constexpr (EPI == EPI_ADDF32) {
          ((float*)Cp)[idx] = v + resid[idx];
        } else {
          float gv = bf2f(other[idx]);
          float sg = gv / (1.f + __expf(-gv));
          ((unsigned short*)Cp)[idx] = f2bf(sg * v);
        }
      }
    }
  }
}

// ===== gemm_gu: fused gate+up, 128x128, BK=64, 4 waves, 48 KB single-buffer ====
// Shared A staged once; dual accumulators; epilogue silu(g)*u -> bf16.
__global__ __launch_bounds__(256) void gemm_gu(const unsigned short* __restrict__ A,
                                               const unsigned short* __restrict__ BG,
                                               const unsigned short* __restrict__ BU,
                                               unsigned short* __restrict__ Cp,
                                               int M, int N, int K) {
  __shared__ unsigned short ldsA[128 * 64];
  __shared__ unsigned short ldsG[128 * 64];
  __shared__ unsigned short ldsU[128 * 64];
  const int tid = threadIdx.x;
  const int w = tid >> 6, lane = tid & 63;
  const int rl = lane & 15, gh = lane >> 4;
  const int wm = (w >> 1) * 64, wn = (w & 1) * 64;

  const int nwg = gridDim.x;
  const int orig = blockIdx.x;
  const int qq = nwg >> 3, rr = nwg & 7;
  const int xcd = orig & 7, lidx = orig >> 3;
  const int fswz = (xcd < rr ? xcd * (qq + 1) : rr * (qq + 1) + (xcd - rr) * qq) + lidx;
  const int MT = M >> 7;
  const int m0 = (fswz % MT) * 128;
  const int n0 = (fswz / MT) * 128;

  const unsigned short* sA[4];
  const unsigned short* sG[4];
  const unsigned short* sU[4];
#pragma unroll
  for (int i = 0; i < 4; ++i) {
    int G = i * 256 + tid, r = G >> 3, sl = (G & 7) ^ (r & 7);
    sA[i] = A + (size_t)(m0 + r) * K + sl * 8;
    sG[i] = BG + (size_t)(n0 + r) * K + sl * 8;
    sU[i] = BU + (size_t)(n0 + r) * K + sl * 8;
  }
  auto STAGE = [&](int kt) {
    const int ko = kt * 64;
#pragma unroll
    for (int i = 0; i < 4; ++i) {
      gload16(sA[i] + ko, &ldsA[(i * 256 + w * 64) * 8]);
      gload16(sG[i] + ko, &ldsG[(i * 256 + w * 64) * 8]);
      gload16(sU[i] + ko, &ldsU[(i * 256 + w * 64) * 8]);
    }
  };

  int aoff[4], boff[4];
#pragma unroll
  for (int i = 0; i < 4; ++i) {
    aoff[i] = (wm + i * 16 + rl) * 64;
    boff[i] = (wn + i * 16 + rl) * 64;
  }

  f32x4 accg[4][4] = {};
  f32x4 accu[4][4] = {};
  const int nk = K >> 6;

  STAGE(0);
  asm volatile("s_waitcnt vmcnt(0)" ::: "memory");
  __builtin_amdgcn_s_barrier();

  for (int kt = 0; kt < nk; ++kt) {
    bf16x8 a[4][2], g[4][2], u[4][2];
#pragma unroll
    for (int i = 0; i < 4; ++i)
#pragma unroll
      for (int ks = 0; ks < 2; ++ks) {
        const int ra = wm + i * 16 + rl;
        const int sla = ((((ks << 2) + gh)) ^ (ra & 7)) * 8;
        a[i][ks] = *(const bf16x8*)&ldsA[aoff[i] + sla];
        const int rb = wn + i * 16 + rl;
        const int slb = ((((ks << 2) + gh)) ^ (rb & 7)) * 8;
        g[i][ks] = *(const bf16x8*)&ldsG[boff[i] + slb];
        u[i][ks] = *(const bf16x8*)&ldsU[boff[i] + slb];
      }
    asm volatile("s_waitcnt lgkmcnt(0)" ::: "memory");
    __builtin_amdgcn_sched_barrier(0);
    // ---- ks=0: gate + up (32 MFMA) before the buffer-free barrier ----
    __builtin_amdgcn_s_setprio(1);
#pragma unroll
    for (int i = 0; i < 4; ++i)
#pragma unroll
      for (int j = 0; j < 4; ++j) {
        accg[i][j] = MFMA16(a[i][0], g[j][0], accg[i][j]);
        accu[i][j] = MFMA16(a[i][0], u[j][0], accu[i][j]);
      }
    __builtin_amdgcn_s_setprio(0);
    __builtin_amdgcn_sched_barrier(0);
    __builtin_amdgcn_s_barrier();
    STAGE((kt + 1 < nk) ? kt + 1 : nk - 1);
    __builtin_amdgcn_sched_barrier(0);
    // ---- ks=1: gate + up (32 MFMA, register-only) fills staging latency ----
    __builtin_amdgcn_s_setprio(1);
#pragma unroll
    for (int i = 0; i < 4; ++i)
#pragma unroll
      for (int j = 0; j < 4; ++j) {
        accg[i][j] = MFMA16(a[i][1], g[j][1], accg[i][j]);
        accu[i][j] = MFMA16(a[i][1], u[j][1], accu[i][j]);
      }
    __builtin_amdgcn_s_setprio(0);
    __builtin_amdgcn_sched_barrier(0);
    asm volatile("s_waitcnt vmcnt(0)" ::: "memory");
    __builtin_amdgcn_s_barrier();
  }

#pragma unroll
  for (int i = 0; i < 4; ++i) {
#pragma unroll
    for (int j = 0; j < 4; ++j) {
#pragma unroll
      for (int rg = 0; rg < 4; ++rg) {
        const int row = m0 + wm + i * 16 + gh * 4 + rg;
        const int col = n0 + wn + j * 16 + rl;
        const float gv = accg[i][j][rg];
        const float uv = accu[i][j][rg];
        const float sg = gv / (1.f + __expf(-gv));
        Cp[(size_t)row * N + col] = f2bf(sg * uv);
      }
    }
  }
}

// ---------------- q repack: [B*S][NH*192] bf16 -> Qc[b,h,s,192] (rope + scale) -------
__global__ __launch_bounds__(256) void repack_q(const unsigned short* __restrict__ q,
                                                const float* __restrict__ cosT,
                                                const float* __restrict__ sinT,
                                                unsigned short* __restrict__ Qc) {
  const int row = blockIdx.x;  // b*S + s
  const int b = row >> 11, s = row & 2047;
  const float scale = 0.07216878364870322f;  // 1/sqrt(192)
  const unsigned short* qr = q + (size_t)row * 3072;
  for (int i = threadIdx.x; i < 3072; i += 256) {
    int h = i / 192, d = i - h * 192;
    float v;
    if (d < 128) {
      v = bf2f(qr[h * 192 + d]);
    } else {
      int j = d - 128;
      int jj = j & 31;
      float x1 = bf2f(qr[h * 192 + 128 + jj]);
      float x2 = bf2f(qr[h * 192 + 160 + jj]);
      float c = cosT[s * 32 + jj], sn = sinT[s * 32 + jj];
      v = (j < 32) ? (x1 * c - x2 * sn) : (x2 * c + x1 * sn);
    }
    Qc[((size_t)(b * 16 + h) * Sc + s) * 192 + d] = f2bf(v * scale);
  }
}

// ------- kv repack: build Kc[b,h,s,192] (nope | roped k_rope) and VT[b,h,f,s] -------
__global__ __launch_bounds__(256) void repack_kv(const unsigned short* __restrict__ kvex,
                                                 const float* __restrict__ kvf,
                                                 const float* __restrict__ cosT,
                                                 const float* __restrict__ sinT,
                                                 unsigned short* __restrict__ Kc,
                                                 unsigned short* __restrict__ VT) {
  __shared__ unsigned short vt_lds[32][136];
  const int bid = blockIdx.x;
  const int st = bid & 63;
  const int h = (bid >> 6) & 15;
  const int b = bid >> 10;
  const int s0 = st * 32;
  const int tid = threadIdx.x;
  const size_t KcBase = (size_t)(b * 16 + h) * Sc;
  for (int i = tid; i < 32 * 32; i += 256) {
    int r = i >> 5, g = i & 31;
    uint4 vdat = *(const uint4*)(kvex + (size_t)(b * Sc + s0 + r) * 4096 + h * 256 + g * 8);
    if (g < 16) {
      *(uint4*)(Kc + (KcBase + s0 + r) * 192 + g * 8) = vdat;
    } else {
      *(uint4*)(&vt_lds[r][(g - 16) * 8]) = vdat;
    }
  }
  for (int i = tid; i < 32 * 64; i += 256) {
    int r = i >> 6, d = i & 63;
    int s = s0 + r;
    int jj = d & 31;
    const float* kvrow = kvf + (size_t)(b * Sc + s) * 640;
    float x1 = kvrow[512 + jj], x2 = kvrow[544 + jj];
    float c = cosT[s * 32 + jj], sn = sinT[s * 32 + jj];
    float v = (d < 32) ? (x1 * c - x2 * sn) : (x2 * c + x1 * sn);
    Kc[(KcBase + s) * 192 + 128 + d] = f2bf(v);
  }
  __syncthreads();
  const int f = tid >> 1, sh = (tid & 1) * 16;
  unsigned int vals[8];
#pragma unroll
  for (int k2 = 0; k2 < 8; ++k2) {
    unsigned int lo = vt_lds[sh + 2 * k2][f];
    unsigned int hi = vt_lds[sh + 2 * k2 + 1][f];
    vals[k2] = lo | (hi << 16);
  }
  unsigned short* dst = VT + ((size_t)(b * 16 + h) * 128 + f) * Sc + s0 + sh;
  ((uint4*)dst)[0] = make_uint4(vals[0], vals[1], vals[2], vals[3]);
  ((uint4*)dst)[1] = make_uint4(vals[4], vals[5], vals[6], vals[7]);
}

// ---------------- flash attention: 8 waves, q-tile 128, KVBLK 64, dbuf ----------------
__global__ __launch_bounds__(512) void attn_k(const unsigned short* __restrict__ Qc,
                                              const unsigned short* __restrict__ Kc,
                                              const unsigned short* __restrict__ VT,
                                              unsigned short* __restrict__ Ob) {
  __shared__ unsigned short lds_k[2][64 * 192];
  __shared__ unsigned short lds_v[2][128 * 64];
  __shared__ __align__(16) unsigned short p_lds[8][16 * 72];
  const int tid = threadIdx.x, w = tid >> 6, lane = tid & 63;
  const int rl = lane & 15, gh = lane >> 4;
  const int bidx = blockIdx.x;
  const int bh = bidx & 31;
  const int qt = 15 - (bidx >> 5);
  const unsigned short* Qh = Qc + (size_t)bh * Sc * 192;
  const unsigned short* Kh = Kc + (size_t)bh * Sc * 192;
  const unsigned short* Vh = VT + (size_t)bh * 128 * Sc;
  const int qr0 = qt * 128 + w * 16;

  bf16x8 qf[6];
#pragma unroll
  for (int kk = 0; kk < 6; ++kk)
    qf[kk] = *(const bf16x8*)(Qh + (size_t)(qr0 + rl) * 192 + kk * 32 + gh * 8);

  f32x4 o[8] = {};
  float mrun[4] = {-1e30f, -1e30f, -1e30f, -1e30f};
  float srun[4] = {0.f, 0.f, 0.f, 0.f};

  int kr[3], kg[3];
#pragma unroll
  for (int j = 0; j < 3; ++j) {
    int G = j * 512 + tid;
    int r = G / 24, gq = G - r * 24;
    kr[j] = r;
    kg[j] = (gq & ~7) | ((gq & 7) ^ (r & 7));
  }
  int vr[2], vg[2];
#pragma unroll
  for (int j = 0; j < 2; ++j) {
    int G = j * 512 + tid;
    int r = G >> 3;
    vr[j] = r;
    vg[j] = (G & 7) ^ (r & 7);
  }

  auto STAGE = [&](int t, int b) {
    const int k0 = t * 64;
#pragma unroll
    for (int j = 0; j < 3; ++j)
      gload16(Kh + (size_t)(k0 + kr[j]) * 192 + kg[j] * 8,
              &lds_k[b][(j * 512 + w * 64) * 8]);
#pragma unroll
    for (int j = 0; j < 2; ++j)
      gload16(Vh + (size_t)vr[j] * Sc + k0 + vg[j] * 8,
              &lds_v[b][(j * 512 + w * 64) * 8]);
  };

  STAGE(0, 0);
  asm volatile("s_waitcnt vmcnt(0)" ::: "memory");
  __builtin_amdgcn_s_barrier();
  __builtin_amdgcn_sched_barrier(0);

  const int nt = 2 * qt + 2;
  int cur = 0;
  for (int t = 0; t < nt; ++t) {
    if (t + 1 < nt) STAGE(t + 1, cur ^ 1);
    const int k0 = t * 64;
    if (k0 <= qr0 + 15) {
      const unsigned short* lk = lds_k[cur];
      const unsigned short* lv = lds_v[cur];
      f32x4 s[4] = {};
      __builtin_amdgcn_s_setprio(1);
#pragma unroll
      for (int kk = 0; kk < 6; ++kk) {
        const int gq = kk * 4 + gh;
#pragma unroll
        for (int ks = 0; ks < 4; ++ks) {
          const int krow = ks * 16 + rl;
          const int ph = (gq & ~7) | ((gq & 7) ^ (krow & 7));
          bf16x8 kf = *(const bf16x8*)&lk[krow * 192 + ph * 8];
          s[ks] = MFMA16(qf[kk], kf, s[ks]);
        }
      }
      __builtin_amdgcn_s_setprio(0);
      if (k0 + 63 > qr0) {
#pragma unroll
        for (int ks = 0; ks < 4; ++ks)
#pragma unroll
          for (int rg = 0; rg < 4; ++rg) {
            int qrow = qr0 + gh * 4 + rg;
            if (k0 + ks * 16 + rl > qrow) s[ks][rg] = -1e30f;
          }
      }
      float tmax[4];
#pragma unroll
      for (int rg = 0; rg < 4; ++rg) {
        float v = fmaxf(fmaxf(s[0][rg], s[1][rg]), fmaxf(s[2][rg], s[3][rg]));
        v = fmaxf(v, __shfl_xor(v, 1));
        v = fmaxf(v, __shfl_xor(v, 2));
        v = fmaxf(v, __shfl_xor(v, 4));
        v = fmaxf(v, __shfl_xor(v, 8));
        tmax[rg] = v;
      }
      int need = !(tmax[0] <= mrun[0] + 8.f && tmax[1] <= mrun[1] + 8.f &&
                   tmax[2] <= mrun[2] + 8.f && tmax[3] <= mrun[3] + 8.f);
      if (__any(need)) {
        float al[4];
#pragma unroll
        for (int rg = 0; rg < 4; ++rg) {
          float mn = fmaxf(mrun[rg], tmax[rg]);
          al[rg] = __expf(mrun[rg] - mn);
          mrun[rg] = mn;
          srun[rg] *= al[rg];
        }
#pragma unroll
        for (int i = 0; i < 8; ++i)
#pragma unroll
          for (int rg = 0; rg < 4; ++rg) o[i][rg] *= al[rg];
      }
      unsigned short* pw = p_lds[w];
#pragma unroll
      for (int ks = 0; ks < 4; ++ks)
#pragma unroll
        for (int rg = 0; rg < 4; ++rg) {
          float p = __expf(s[ks][rg] - mrun[rg]);
          srun[rg] += p;
          pw[(gh * 4 + rg) * 72 + ks * 16 + rl] = f2bf(p);
        }
      bf16x8 pa0 = *(const bf16x8*)&pw[rl * 72 + 0 * 32 + gh * 8];
      bf16x8 pa1 = *(const bf16x8*)&pw[rl * 72 + 1 * 32 + gh * 8];
      __builtin_amdgcn_s_setprio(1);
#pragma unroll
      for (int vf = 0; vf < 8; ++vf) {
        const int row = vf * 16 + rl;
        bf16x8 v0 = *(const bf16x8*)&lv[row * 64 + ((0 * 4 + gh) ^ (row & 7)) * 8];
        o[vf] = MFMA16(pa0, v0, o[vf]);
        bf16x8 v1 = *(const bf16x8*)&lv[row * 64 + ((1 * 4 + gh) ^ (row & 7)) * 8];
        o[vf] = MFMA16(pa1, v1, o[vf]);
      }
      __builtin_amdgcn_s_setprio(0);
    }
    asm volatile("s_waitcnt vmcnt(0)" ::: "memory");
    __builtin_amdgcn_s_barrier();
    __builtin_amdgcn_sched_barrier(0);
    cur ^= 1;
  }
  float rd[4];
#pragma unroll
  for (int rg = 0; rg < 4; ++rg) {
    float rs = srun[rg];
    rs += __shfl_xor(rs, 1);
    rs += __shfl_xor(rs, 2);
    rs += __shfl_xor(rs, 4);
    rs += __shfl_xor(rs, 8);
    rd[rg] = 1.f / rs;
  }
  const int b = bh >> 4, hh = bh & 15;
#pragma unroll
  for (int vf = 0; vf < 8; ++vf) {
#pragma unroll
    for (int rg = 0; rg < 4; ++rg) {
      int srow = qr0 + gh * 4 + rg;
      int col = hh * 128 + vf * 16 + rl;
      Ob[((size_t)(b * Sc) + srow) * 2048 + col] = f2bf(o[vf][rg] * rd[rg]);
    }
  }
}

// ---------------- host ----------------
extern "C" void kernel_launch(void* const* d_in, const int* in_sizes, int n_in,
                              void* d_out, int out_size, void* d_ws, size_t ws_size,
                              hipStream_t stream) {
  (void)in_sizes; (void)n_in;
  const float* x    = (const float*)d_in[0];
  const float* anw  = (const float*)d_in[1];
  const float* wqd  = (const float*)d_in[2];
  const float* wqu  = (const float*)d_in[3];
  const float* wkvd = (const float*)d_in[4];
  const float* kvnw = (const float*)d_in[5];
  const float* wkvu = (const float*)d_in[6];
  const float* wout = (const float*)d_in[7];
  const float* fnw  = (const float*)d_in[8];
  const float* wg   = (const float*)d_in[9];
  const float* wu   = (const float*)d_in[10];
  const float* wd   = (const float*)d_in[11];
  float* out = (float*)d_out;

  char* ws = (char*)d_ws;
  size_t off = 0;
  auto alloc = [&](size_t bytes) -> char* {
    char* p = ws + off;
    off += (bytes + 255) & ~(size_t)255;
    return p;
  };
  unsigned short* wslot = (unsigned short*)alloc(5632ull * 2048 * 2);
  float* cosT           = (float*)alloc(2048ull * 32 * 4);
  float* sinT           = (float*)alloc(2048ull * 32 * 4);
  unsigned short* hbuf  = (unsigned short*)alloc(4096ull * 2048 * 2);
  char* arena           = alloc(4096ull * 1536 * 2 + 4096ull * 3072 * 2);
  float* kvf            = (float*)alloc(4096ull * 640 * 4);
  unsigned short* kvn   = (unsigned short*)alloc(4096ull * 512 * 2);
  unsigned short* Qc    = (unsigned short*)alloc(32ull * 2048 * 192 * 2);
  unsigned short* Kc    = (unsigned short*)alloc(32ull * 2048 * 192 * 2);
  unsigned short* VTb   = (unsigned short*)alloc(32ull * 128 * 2048 * 2);
  const size_t NEED = off;

  if (ws_size < NEED) {
    fill_k<<<dim3((out_size + 255) / 256), dim3(256), 0, stream>>>(
        out, (float)(ws_size >> 20), out_size);
    return;
  }

  unsigned short* qd    = (unsigned short*)arena;
  unsigned short* q     = (unsigned short*)(arena + 4096ull * 1536 * 2);
  unsigned short* kvex  = (unsigned short*)arena;
  unsigned short* wslot2 = (unsigned short*)arena;  // WuT after kvex dead (37.7 >= 23.1 MB)
  unsigned short* h     = hbuf;
  unsigned short* attnb = hbuf;
  unsigned short* h2    = hbuf;
  unsigned short* gbuf  = Qc;
  float* x2             = out;

  dim3 blk(256), blk512(512);
  rope_tab<<<dim3(256), blk, 0, stream>>>(cosT, sinT);
  rmsnorm_k<<<dim3(4096), blk, 0, stream>>>(x, anw, h, 2048, 2048, 2048);

  // q path
  wtrans<<<dim3(24, 32), blk, 0, stream>>>(wqd, wslot, 2048, 1536);
  gemm_sb1<EPI_BF16><<<dim3(32 * 12), blk, 0, stream>>>(h, wslot, qd, nullptr, nullptr, 4096, 1536, 2048);
  wtrans<<<dim3(48, 24), blk, 0, stream>>>(wqu, wslot, 1536, 3072);
  gemm_sb1<EPI_BF16><<<dim3(32 * 24), blk, 0, stream>>>(qd, wslot, q, nullptr, nullptr, 4096, 3072, 1536);
  repack_q<<<dim3(4096), blk, 0, stream>>>(q, cosT, sinT, Qc);

  // kv path
  wtrans<<<dim3(9, 32), blk, 0, stream>>>(wkvd, wslot, 2048, 576);
  gemm_sb1<EPI_F32><<<dim3(32 * 5), blk, 0, stream>>>(h, wslot, kvf, nullptr, nullptr, 4096, 640, 2048);
  rmsnorm_k<<<dim3(4096), blk, 0, stream>>>(kvf, kvnw, kvn, 512, 640, 512);
  wtrans<<<dim3(64, 8), blk, 0, stream>>>(wkvu, wslot, 512, 4096);
  gemm_sb1<EPI_BF16><<<dim3(32 * 32), blk, 0, stream>>>(kvn, wslot, kvex, nullptr, nullptr, 4096, 4096, 512);
  repack_kv<<<dim3(2048), blk, 0, stream>>>(kvex, kvf, cosT, sinT, Kc, VTb);

  // attention
  attn_k<<<dim3(512), blk512, 0, stream>>>(Qc, Kc, VTb, attnb);
  wtrans<<<dim3(32, 32), blk, 0, stream>>>(wout, wslot, 2048, 2048);
  gemm_sb1<EPI_ADDF32><<<dim3(32 * 16), blk, 0, stream>>>(attnb, wslot, x2, x, nullptr, 4096, 2048, 2048);

  // ffn path (fused gate+up; WuT in arena — kvex dead after repack_kv)
  rmsnorm_k<<<dim3(4096), blk, 0, stream>>>(x2, fnw, h2, 2048, 2048, 2048);
  wtrans<<<dim3(88, 32), blk, 0, stream>>>(wg, wslot, 2048, 5632);
  wtrans<<<dim3(88, 32), blk, 0, stream>>>(wu, wslot2, 2048, 5632);
  gemm_gu<<<dim3(32 * 44), blk, 0, stream>>>(h2, wslot, wslot2, gbuf, 4096, 5632, 2048);
  wtrans<<<dim3(32, 88), blk, 0, stream>>>(wd, wslot, 5632, 2048);
  gemm_sb1<EPI_ADDF32><<<dim3(32 * 16), blk, 0, stream>>>(gbuf, wslot, out, x2, nullptr, 4096, 2048, 5632);
}

// Round 15
// 832.953 us; speedup vs baseline: 1.0481x; 1.0481x over previous
//
#include <hip/hip_runtime.h>
#include <hip/hip_bf16.h>

// MLA transformer block, bf16 MFMA implementation.
// R15: revert gemm_gu (regressed: VGPR 192 -> occ 10%, FETCH 395MB). Back to R11.
//      A/B: gate -> gemm_sb3 (128x256 block, 4 waves of 64x128 wave tiles,
//      48KB single-buffer, 34.3 KB/MFLOP LDS traffic, R11-split loop); up stays sb1.

using bf16x8 = __attribute__((ext_vector_type(8))) short;
using f32x4  = __attribute__((ext_vector_type(4))) float;

#define GLOBAL_AS __attribute__((address_space(1)))
#define LDS_AS    __attribute__((address_space(3)))
#define MFMA16(a, b, c) __builtin_amdgcn_mfma_f32_16x16x32_bf16((a), (b), (c), 0, 0, 0)

static constexpr int Sc = 2048;

__device__ __forceinline__ void gload16(const void* g, void* l) {
  __builtin_amdgcn_global_load_lds((const GLOBAL_AS unsigned int*)g,
                                   (LDS_AS unsigned int*)l, 16, 0, 0);
}
__device__ __forceinline__ float bf2f(unsigned short u) {
  union { float f; unsigned int i; } x; x.i = ((unsigned int)u) << 16; return x.f;
}
__device__ __forceinline__ unsigned short f2bf(float f) {
  union { float f; unsigned int i; } x; x.f = f;
  unsigned int i = x.i;
  return (unsigned short)((i + 0x7fffu + ((i >> 16) & 1u)) >> 16);
}
__device__ __forceinline__ int swz4(int r) { return ((r >> 2) & 3) ^ (r & 3); }

// ---------------- diagnostic fill (ws too small beacon) ----------------
__global__ void fill_k(float* out, float v, int n) {
  int i = blockIdx.x * 256 + threadIdx.x;
  if (i < n) out[i] = v;
}

// -------- weight transpose+cast: W[K][N] f32 -> WT[N][K] bf16, 64n x 64k tiles ------
__global__ __launch_bounds__(256) void wtrans(const float* __restrict__ W,
                                              unsigned short* __restrict__ WT,
                                              int K, int N) {
  __shared__ float t[64][65];
  const int n0 = blockIdx.x * 64, k0 = blockIdx.y * 64;
  const int tx = threadIdx.x & 15, ty = threadIdx.x >> 4;  // tx: n-gran, ty: k row
#pragma unroll
  for (int i = 0; i < 4; ++i) {
    int k = k0 + ty + i * 16;
    const float4 v = *(const float4*)(W + (size_t)k * N + n0 + tx * 4);
    t[ty + i * 16][tx * 4 + 0] = v.x;
    t[ty + i * 16][tx * 4 + 1] = v.y;
    t[ty + i * 16][tx * 4 + 2] = v.z;
    t[ty + i * 16][tx * 4 + 3] = v.w;
  }
  __syncthreads();
  const int kx = threadIdx.x & 7, ny = threadIdx.x >> 3;  // kx: k-octet, ny 0..31
#pragma unroll
  for (int i = 0; i < 2; ++i) {
    int nl = ny + i * 32;
    unsigned short u[8];
#pragma unroll
    for (int j = 0; j < 8; ++j) u[j] = f2bf(t[kx * 8 + j][nl]);
    *(uint4*)(WT + (size_t)(n0 + nl) * K + k0 + kx * 8) = *(uint4*)u;
  }
}

// ---------------- rope tables ----------------
__global__ void rope_tab(float* __restrict__ cosT, float* __restrict__ sinT) {
  int i = blockIdx.x * 256 + threadIdx.x;
  if (i >= Sc * 32) return;
  int s = i >> 5, j = i & 31;
  float inv = powf(10000.0f, -(float)j / 32.0f);
  float a = (float)s * inv;
  cosT[i] = cosf(a);
  sinT[i] = sinf(a);
}

// ---------------- rmsnorm (f32 in, bf16 out) ----------------
__global__ __launch_bounds__(256) void rmsnorm_k(const float* __restrict__ in,
                                                 const float* __restrict__ w,
                                                 unsigned short* __restrict__ out,
                                                 int D, int istride, int ostride) {
  const int row = blockIdx.x;
  const float* x = in + (size_t)row * istride;
  float ss = 0.f;
  for (int c = threadIdx.x * 4; c < D; c += 1024) {
    const float4 v = *(const float4*)(x + c);
    ss += v.x * v.x + v.y * v.y + v.z * v.z + v.w * v.w;
  }
#pragma unroll
  for (int off = 1; off < 64; off <<= 1) ss += __shfl_xor(ss, off);
  __shared__ float part[4];
  if ((threadIdx.x & 63) == 0) part[threadIdx.x >> 6] = ss;
  __syncthreads();
  float tot = part[0] + part[1] + part[2] + part[3];
  float r = rsqrtf(tot / (float)D + 1e-6f);
  for (int c = threadIdx.x * 4; c < D; c += 1024) {
    const float4 v = *(const float4*)(x + c);
    ushort4 o;
    o.x = f2bf(v.x * r * w[c + 0]);
    o.y = f2bf(v.y * r * w[c + 1]);
    o.z = f2bf(v.z * r * w[c + 2]);
    o.w = f2bf(v.w * r * w[c + 3]);
    *(ushort4*)(out + (size_t)row * ostride + c) = o;
  }
}

enum { EPI_BF16 = 0, EPI_F32 = 1, EPI_ADDF32 = 2, EPI_SILU = 3 };

// ===== gemm_sb1: 128x128, BK=64, 4 waves, SINGLE-buffer LDS (32 KB) — R11 split ====
template <int EPI>
__global__ __launch_bounds__(256) void gemm_sb1(const unsigned short* __restrict__ A,
                                                const unsigned short* __restrict__ BT,
                                                void* __restrict__ Cp,
                                                const float* __restrict__ resid,
                                                const unsigned short* __restrict__ other,
                                                int M, int N, int K) {
  __shared__ unsigned short ldsA[128 * 64];
  __shared__ unsigned short ldsB[128 * 64];
  const int tid = threadIdx.x;
  const int w = tid >> 6, lane = tid & 63;
  const int rl = lane & 15, gh = lane >> 4;
  const int wm = (w >> 1) * 64, wn = (w & 1) * 64;

  const int nwg = gridDim.x;
  const int orig = blockIdx.x;
  const int qq = nwg >> 3, rr = nwg & 7;
  const int xcd = orig & 7, lidx = orig >> 3;
  const int fswz = (xcd < rr ? xcd * (qq + 1) : rr * (qq + 1) + (xcd - rr) * qq) + lidx;
  const int MT = M >> 7;
  const int m0 = (fswz % MT) * 128;
  const int n0 = (fswz / MT) * 128;

  const unsigned short* sA[4];
  const unsigned short* sB[4];
#pragma unroll
  for (int i = 0; i < 4; ++i) {
    int G = i * 256 + tid, r = G >> 3, sl = (G & 7) ^ (r & 7);
    sA[i] = A + (size_t)(m0 + r) * K + sl * 8;
    sB[i] = BT + (size_t)(n0 + r) * K + sl * 8;
  }
  auto STAGE = [&](int kt) {
    const int ko = kt * 64;
#pragma unroll
    for (int i = 0; i < 4; ++i) {
      gload16(sA[i] + ko, &ldsA[(i * 256 + w * 64) * 8]);
      gload16(sB[i] + ko, &ldsB[(i * 256 + w * 64) * 8]);
    }
  };

  int aoff[4], boff[4];
#pragma unroll
  for (int i = 0; i < 4; ++i) {
    aoff[i] = (wm + i * 16 + rl) * 64;
    boff[i] = (wn + i * 16 + rl) * 64;
  }

  f32x4 acc[4][4] = {};
  const int nk = K >> 6;

  STAGE(0);
  asm volatile("s_waitcnt vmcnt(0)" ::: "memory");
  __builtin_amdgcn_s_barrier();

  for (int kt = 0; kt < nk; ++kt) {
    bf16x8 a[4][2], b[4][2];
#pragma unroll
    for (int i = 0; i < 4; ++i)
#pragma unroll
      for (int ks = 0; ks < 2; ++ks) {
        const int ra = wm + i * 16 + rl;
        a[i][ks] = *(const bf16x8*)&ldsA[aoff[i] + ((((ks << 2) + gh)) ^ (ra & 7)) * 8];
        const int rb = wn + i * 16 + rl;
        b[i][ks] = *(const bf16x8*)&ldsB[boff[i] + ((((ks << 2) + gh)) ^ (rb & 7)) * 8];
      }
    asm volatile("s_waitcnt lgkmcnt(0)" ::: "memory");
    __builtin_amdgcn_sched_barrier(0);
    __builtin_amdgcn_s_setprio(1);
#pragma unroll
    for (int i = 0; i < 4; ++i)
#pragma unroll
      for (int j = 0; j < 4; ++j) acc[i][j] = MFMA16(a[i][0], b[j][0], acc[i][j]);
    __builtin_amdgcn_s_setprio(0);
    __builtin_amdgcn_sched_barrier(0);
    __builtin_amdgcn_s_barrier();
    STAGE((kt + 1 < nk) ? kt + 1 : nk - 1);
    __builtin_amdgcn_sched_barrier(0);
    __builtin_amdgcn_s_setprio(1);
#pragma unroll
    for (int i = 0; i < 4; ++i)
#pragma unroll
      for (int j = 0; j < 4; ++j) acc[i][j] = MFMA16(a[i][1], b[j][1], acc[i][j]);
    __builtin_amdgcn_s_setprio(0);
    __builtin_amdgcn_sched_barrier(0);
    asm volatile("s_waitcnt vmcnt(0)" ::: "memory");
    __builtin_amdgcn_s_barrier();
  }

#pragma unroll
  for (int i = 0; i < 4; ++i) {
#pragma unroll
    for (int j = 0; j < 4; ++j) {
#pragma unroll
      for (int rg = 0; rg < 4; ++rg) {
        const int row = m0 + wm + i * 16 + gh * 4 + rg;
        const int col = n0 + wn + j * 16 + rl;
        const size_t idx = (size_t)row * N + col;
        const float v = acc[i][j][rg];
        if constexpr (EPI == EPI_BF16) {
          ((unsigned short*)Cp)[idx] = f2bf(v);
        } else if constexpr (EPI == EPI_F32) {
          ((float*)Cp)[idx] = v;
        } else if constexpr (EPI == EPI_ADDF32) {
          ((float*)Cp)[idx] = v + resid[idx];
        } else {
          float gv = bf2f(other[idx]);
          float sg = gv / (1.f + __expf(-gv));
          ((unsigned short*)Cp)[idx] = f2bf(sg * v);
        }
      }
    }
  }
}

// ===== gemm_sb3: 128x256 block, 4 waves of 64x128 wave tiles, 48KB single-buffer ====
// Same R11-split loop; LDS traffic 34.3 KB/MFLOP (vs sb1 45.7). ~230 VGPR, 2 blk/CU.
template <int EPI>
__global__ __launch_bounds__(256) void gemm_sb3(const unsigned short* __restrict__ A,
                                                const unsigned short* __restrict__ BT,
                                                void* __restrict__ Cp,
                                                const float* __restrict__ resid,
                                                const unsigned short* __restrict__ other,
                                                int M, int N, int K) {
  __shared__ unsigned short ldsA[128 * 64];   // 16 KB
  __shared__ unsigned short ldsB[256 * 64];   // 32 KB
  const int tid = threadIdx.x;
  const int w = tid >> 6, lane = tid & 63;
  const int rl = lane & 15, gh = lane >> 4;
  const int wm = (w >> 1) * 64, wn = (w & 1) * 128;

  const int nwg = gridDim.x;
  const int orig = blockIdx.x;
  const int qq = nwg >> 3, rr = nwg & 7;
  const int xcd = orig & 7, lidx = orig >> 3;
  const int fswz = (xcd < rr ? xcd * (qq + 1) : rr * (qq + 1) + (xcd - rr) * qq) + lidx;
  const int MT = M >> 7;
  const int m0 = (fswz % MT) * 128;
  const int n0 = (fswz / MT) * 256;

  // A: 1024 granules -> 4/thread; B: 2048 granules -> 8/thread
  const unsigned short* sA[4];
  const unsigned short* sB[8];
#pragma unroll
  for (int i = 0; i < 4; ++i) {
    int G = i * 256 + tid, r = G >> 3, sl = (G & 7) ^ (r & 7);
    sA[i] = A + (size_t)(m0 + r) * K + sl * 8;
  }
#pragma unroll
  for (int i = 0; i < 8; ++i) {
    int G = i * 256 + tid, r = G >> 3, sl = (G & 7) ^ (r & 7);
    sB[i] = BT + (size_t)(n0 + r) * K + sl * 8;
  }
  auto STAGE = [&](int kt) {
    const int ko = kt * 64;
#pragma unroll
    for (int i = 0; i < 4; ++i)
      gload16(sA[i] + ko, &ldsA[(i * 256 + w * 64) * 8]);
#pragma unroll
    for (int i = 0; i < 8; ++i)
      gload16(sB[i] + ko, &ldsB[(i * 256 + w * 64) * 8]);
  };

  int aoff[4], boff[8];
#pragma unroll
  for (int i = 0; i < 4; ++i) aoff[i] = (wm + i * 16 + rl) * 64;
#pragma unroll
  for (int j = 0; j < 8; ++j) boff[j] = (wn + j * 16 + rl) * 64;

  f32x4 acc[4][8] = {};
  const int nk = K >> 6;

  STAGE(0);
  asm volatile("s_waitcnt vmcnt(0)" ::: "memory");
  __builtin_amdgcn_s_barrier();

  for (int kt = 0; kt < nk; ++kt) {
    bf16x8 a[4][2], b[8][2];
#pragma unroll
    for (int i = 0; i < 4; ++i)
#pragma unroll
      for (int ks = 0; ks < 2; ++ks) {
        const int ra = wm + i * 16 + rl;
        a[i][ks] = *(const bf16x8*)&ldsA[aoff[i] + ((((ks << 2) + gh)) ^ (ra & 7)) * 8];
      }
#pragma unroll
    for (int j = 0; j < 8; ++j)
#pragma unroll
      for (int ks = 0; ks < 2; ++ks) {
        const int rb = wn + j * 16 + rl;
        b[j][ks] = *(const bf16x8*)&ldsB[boff[j] + ((((ks << 2) + gh)) ^ (rb & 7)) * 8];
      }
    asm volatile("s_waitcnt lgkmcnt(0)" ::: "memory");
    __builtin_amdgcn_sched_barrier(0);
    // ---- ks=0 (32 MFMA) before the buffer-free barrier ----
    __builtin_amdgcn_s_setprio(1);
#pragma unroll
    for (int i = 0; i < 4; ++i)
#pragma unroll
      for (int j = 0; j < 8; ++j) acc[i][j] = MFMA16(a[i][0], b[j][0], acc[i][j]);
    __builtin_amdgcn_s_setprio(0);
    __builtin_amdgcn_sched_barrier(0);
    __builtin_amdgcn_s_barrier();
    STAGE((kt + 1 < nk) ? kt + 1 : nk - 1);
    __builtin_amdgcn_sched_barrier(0);
    // ---- ks=1 (32 MFMA, register-only) fills staging latency ----
    __builtin_amdgcn_s_setprio(1);
#pragma unroll
    for (int i = 0; i < 4; ++i)
#pragma unroll
      for (int j = 0; j < 8; ++j) acc[i][j] = MFMA16(a[i][1], b[j][1], acc[i][j]);
    __builtin_amdgcn_s_setprio(0);
    __builtin_amdgcn_sched_barrier(0);
    asm volatile("s_waitcnt vmcnt(0)" ::: "memory");
    __builtin_amdgcn_s_barrier();
  }

#pragma unroll
  for (int i = 0; i < 4; ++i) {
#pragma unroll
    for (int j = 0; j < 8; ++j) {
#pragma unroll
      for (int rg = 0; rg < 4; ++rg) {
        const int row = m0 + wm + i * 16 + gh * 4 + rg;
        const int col = n0 + wn + j * 16 + rl;
        const size_t idx = (size_t)row * N + col;
        const float v = acc[i][j][rg];
        if constexpr (EPI == EPI_BF16) {
          ((unsigned short*)Cp)[idx] = f2bf(v);
        } else if constexpr (EPI == EPI_F32) {
          ((float*)Cp)[idx] = v;
        } else if constexpr (EPI == EPI_ADDF32) {
          ((float*)Cp)[idx] = v + resid[idx];
        } else {
          float gv = bf2f(other[idx]);
          float sg = gv / (1.f + __expf(-gv));
          ((unsigned short*)Cp)[idx] = f2bf(sg * v);
        }
      }
    }
  }
}

// ---------------- q repack: [B*S][NH*192] bf16 -> Qc[b,h,s,192] (rope + scale) -------
__global__ __launch_bounds__(256) void repack_q(const unsigned short* __restrict__ q,
                                                const float* __restrict__ cosT,
                                                const float* __restrict__ sinT,
                                                unsigned short* __restrict__ Qc) {
  const int row = blockIdx.x;  // b*S + s
  const int b = row >> 11, s = row & 2047;
  const float scale = 0.07216878364870322f;  // 1/sqrt(192)
  const unsigned short* qr = q + (size_t)row * 3072;
  for (int i = threadIdx.x; i < 3072; i += 256) {
    int h = i / 192, d = i - h * 192;
    float v;
    if (d < 128) {
      v = bf2f(qr[h * 192 + d]);
    } else {
      int j = d - 128;
      int jj = j & 31;
      float x1 = bf2f(qr[h * 192 + 128 + jj]);
      float x2 = bf2f(qr[h * 192 + 160 + jj]);
      float c = cosT[s * 32 + jj], sn = sinT[s * 32 + jj];
      v = (j < 32) ? (x1 * c - x2 * sn) : (x2 * c + x1 * sn);
    }
    Qc[((size_t)(b * 16 + h) * Sc + s) * 192 + d] = f2bf(v * scale);
  }
}

// ------- kv repack: build Kc[b,h,s,192] (nope | roped k_rope) and VT[b,h,f,s] -------
__global__ __launch_bounds__(256) void repack_kv(const unsigned short* __restrict__ kvex,
                                                 const float* __restrict__ kvf,
                                                 const float* __restrict__ cosT,
                                                 const float* __restrict__ sinT,
                                                 unsigned short* __restrict__ Kc,
                                                 unsigned short* __restrict__ VT) {
  __shared__ unsigned short vt_lds[32][136];
  const int bid = blockIdx.x;
  const int st = bid & 63;
  const int h = (bid >> 6) & 15;
  const int b = bid >> 10;
  const int s0 = st * 32;
  const int tid = threadIdx.x;
  const size_t KcBase = (size_t)(b * 16 + h) * Sc;
  for (int i = tid; i < 32 * 32; i += 256) {
    int r = i >> 5, g = i & 31;
    uint4 vdat = *(const uint4*)(kvex + (size_t)(b * Sc + s0 + r) * 4096 + h * 256 + g * 8);
    if (g < 16) {
      *(uint4*)(Kc + (KcBase + s0 + r) * 192 + g * 8) = vdat;
    } else {
      *(uint4*)(&vt_lds[r][(g - 16) * 8]) = vdat;
    }
  }
  for (int i = tid; i < 32 * 64; i += 256) {
    int r = i >> 6, d = i & 63;
    int s = s0 + r;
    int jj = d & 31;
    const float* kvrow = kvf + (size_t)(b * Sc + s) * 640;
    float x1 = kvrow[512 + jj], x2 = kvrow[544 + jj];
    float c = cosT[s * 32 + jj], sn = sinT[s * 32 + jj];
    float v = (d < 32) ? (x1 * c - x2 * sn) : (x2 * c + x1 * sn);
    Kc[(KcBase + s) * 192 + 128 + d] = f2bf(v);
  }
  __syncthreads();
  const int f = tid >> 1, sh = (tid & 1) * 16;
  unsigned int vals[8];
#pragma unroll
  for (int k2 = 0; k2 < 8; ++k2) {
    unsigned int lo = vt_lds[sh + 2 * k2][f];
    unsigned int hi = vt_lds[sh + 2 * k2 + 1][f];
    vals[k2] = lo | (hi << 16);
  }
  unsigned short* dst = VT + ((size_t)(b * 16 + h) * 128 + f) * Sc + s0 + sh;
  ((uint4*)dst)[0] = make_uint4(vals[0], vals[1], vals[2], vals[3]);
  ((uint4*)dst)[1] = make_uint4(vals[4], vals[5], vals[6], vals[7]);
}

// ---------------- flash attention: 8 waves, q-tile 128, KVBLK 64, dbuf ----------------
__global__ __launch_bounds__(512) void attn_k(const unsigned short* __restrict__ Qc,
                                              const unsigned short* __restrict__ Kc,
                                              const unsigned short* __restrict__ VT,
                                              unsigned short* __restrict__ Ob) {
  __shared__ unsigned short lds_k[2][64 * 192];
  __shared__ unsigned short lds_v[2][128 * 64];
  __shared__ __align__(16) unsigned short p_lds[8][16 * 72];
  const int tid = threadIdx.x, w = tid >> 6, lane = tid & 63;
  const int rl = lane & 15, gh = lane >> 4;
  const int bidx = blockIdx.x;
  const int bh = bidx & 31;
  const int qt = 15 - (bidx >> 5);
  const unsigned short* Qh = Qc + (size_t)bh * Sc * 192;
  const unsigned short* Kh = Kc + (size_t)bh * Sc * 192;
  const unsigned short* Vh = VT + (size_t)bh * 128 * Sc;
  const int qr0 = qt * 128 + w * 16;

  bf16x8 qf[6];
#pragma unroll
  for (int kk = 0; kk < 6; ++kk)
    qf[kk] = *(const bf16x8*)(Qh + (size_t)(qr0 + rl) * 192 + kk * 32 + gh * 8);

  f32x4 o[8] = {};
  float mrun[4] = {-1e30f, -1e30f, -1e30f, -1e30f};
  float srun[4] = {0.f, 0.f, 0.f, 0.f};

  int kr[3], kg[3];
#pragma unroll
  for (int j = 0; j < 3; ++j) {
    int G = j * 512 + tid;
    int r = G / 24, gq = G - r * 24;
    kr[j] = r;
    kg[j] = (gq & ~7) | ((gq & 7) ^ (r & 7));
  }
  int vr[2], vg[2];
#pragma unroll
  for (int j = 0; j < 2; ++j) {
    int G = j * 512 + tid;
    int r = G >> 3;
    vr[j] = r;
    vg[j] = (G & 7) ^ (r & 7);
  }

  auto STAGE = [&](int t, int b) {
    const int k0 = t * 64;
#pragma unroll
    for (int j = 0; j < 3; ++j)
      gload16(Kh + (size_t)(k0 + kr[j]) * 192 + kg[j] * 8,
              &lds_k[b][(j * 512 + w * 64) * 8]);
#pragma unroll
    for (int j = 0; j < 2; ++j)
      gload16(Vh + (size_t)vr[j] * Sc + k0 + vg[j] * 8,
              &lds_v[b][(j * 512 + w * 64) * 8]);
  };

  STAGE(0, 0);
  asm volatile("s_waitcnt vmcnt(0)" ::: "memory");
  __builtin_amdgcn_s_barrier();
  __builtin_amdgcn_sched_barrier(0);

  const int nt = 2 * qt + 2;
  int cur = 0;
  for (int t = 0; t < nt; ++t) {
    if (t + 1 < nt) STAGE(t + 1, cur ^ 1);
    const int k0 = t * 64;
    if (k0 <= qr0 + 15) {
      const unsigned short* lk = lds_k[cur];
      const unsigned short* lv = lds_v[cur];
      f32x4 s[4] = {};
      __builtin_amdgcn_s_setprio(1);
#pragma unroll
      for (int kk = 0; kk < 6; ++kk) {
        const int gq = kk * 4 + gh;
#pragma unroll
        for (int ks = 0; ks < 4; ++ks) {
          const int krow = ks * 16 + rl;
          const int ph = (gq & ~7) | ((gq & 7) ^ (krow & 7));
          bf16x8 kf = *(const bf16x8*)&lk[krow * 192 + ph * 8];
          s[ks] = MFMA16(qf[kk], kf, s[ks]);
        }
      }
      __builtin_amdgcn_s_setprio(0);
      if (k0 + 63 > qr0) {
#pragma unroll
        for (int ks = 0; ks < 4; ++ks)
#pragma unroll
          for (int rg = 0; rg < 4; ++rg) {
            int qrow = qr0 + gh * 4 + rg;
            if (k0 + ks * 16 + rl > qrow) s[ks][rg] = -1e30f;
          }
      }
      float tmax[4];
#pragma unroll
      for (int rg = 0; rg < 4; ++rg) {
        float v = fmaxf(fmaxf(s[0][rg], s[1][rg]), fmaxf(s[2][rg], s[3][rg]));
        v = fmaxf(v, __shfl_xor(v, 1));
        v = fmaxf(v, __shfl_xor(v, 2));
        v = fmaxf(v, __shfl_xor(v, 4));
        v = fmaxf(v, __shfl_xor(v, 8));
        tmax[rg] = v;
      }
      int need = !(tmax[0] <= mrun[0] + 8.f && tmax[1] <= mrun[1] + 8.f &&
                   tmax[2] <= mrun[2] + 8.f && tmax[3] <= mrun[3] + 8.f);
      if (__any(need)) {
        float al[4];
#pragma unroll
        for (int rg = 0; rg < 4; ++rg) {
          float mn = fmaxf(mrun[rg], tmax[rg]);
          al[rg] = __expf(mrun[rg] - mn);
          mrun[rg] = mn;
          srun[rg] *= al[rg];
        }
#pragma unroll
        for (int i = 0; i < 8; ++i)
#pragma unroll
          for (int rg = 0; rg < 4; ++rg) o[i][rg] *= al[rg];
      }
      unsigned short* pw = p_lds[w];
#pragma unroll
      for (int ks = 0; ks < 4; ++ks)
#pragma unroll
        for (int rg = 0; rg < 4; ++rg) {
          float p = __expf(s[ks][rg] - mrun[rg]);
          srun[rg] += p;
          pw[(gh * 4 + rg) * 72 + ks * 16 + rl] = f2bf(p);
        }
      bf16x8 pa0 = *(const bf16x8*)&pw[rl * 72 + 0 * 32 + gh * 8];
      bf16x8 pa1 = *(const bf16x8*)&pw[rl * 72 + 1 * 32 + gh * 8];
      __builtin_amdgcn_s_setprio(1);
#pragma unroll
      for (int vf = 0; vf < 8; ++vf) {
        const int row = vf * 16 + rl;
        bf16x8 v0 = *(const bf16x8*)&lv[row * 64 + ((0 * 4 + gh) ^ (row & 7)) * 8];
        o[vf] = MFMA16(pa0, v0, o[vf]);
        bf16x8 v1 = *(const bf16x8*)&lv[row * 64 + ((1 * 4 + gh) ^ (row & 7)) * 8];
        o[vf] = MFMA16(pa1, v1, o[vf]);
      }
      __builtin_amdgcn_s_setprio(0);
    }
    asm volatile("s_waitcnt vmcnt(0)" ::: "memory");
    __builtin_amdgcn_s_barrier();
    __builtin_amdgcn_sched_barrier(0);
    cur ^= 1;
  }
  float rd[4];
#pragma unroll
  for (int rg = 0; rg < 4; ++rg) {
    float rs = srun[rg];
    rs += __shfl_xor(rs, 1);
    rs += __shfl_xor(rs, 2);
    rs += __shfl_xor(rs, 4);
    rs += __shfl_xor(rs, 8);
    rd[rg] = 1.f / rs;
  }
  const int b = bh >> 4, hh = bh & 15;
#pragma unroll
  for (int vf = 0; vf < 8; ++vf) {
#pragma unroll
    for (int rg = 0; rg < 4; ++rg) {
      int srow = qr0 + gh * 4 + rg;
      int col = hh * 128 + vf * 16 + rl;
      Ob[((size_t)(b * Sc) + srow) * 2048 + col] = f2bf(o[vf][rg] * rd[rg]);
    }
  }
}

// ---------------- host ----------------
extern "C" void kernel_launch(void* const* d_in, const int* in_sizes, int n_in,
                              void* d_out, int out_size, void* d_ws, size_t ws_size,
                              hipStream_t stream) {
  (void)in_sizes; (void)n_in;
  const float* x    = (const float*)d_in[0];
  const float* anw  = (const float*)d_in[1];
  const float* wqd  = (const float*)d_in[2];
  const float* wqu  = (const float*)d_in[3];
  const float* wkvd = (const float*)d_in[4];
  const float* kvnw = (const float*)d_in[5];
  const float* wkvu = (const float*)d_in[6];
  const float* wout = (const float*)d_in[7];
  const float* fnw  = (const float*)d_in[8];
  const float* wg   = (const float*)d_in[9];
  const float* wu   = (const float*)d_in[10];
  const float* wd   = (const float*)d_in[11];
  float* out = (float*)d_out;

  char* ws = (char*)d_ws;
  size_t off = 0;
  auto alloc = [&](size_t bytes) -> char* {
    char* p = ws + off;
    off += (bytes + 255) & ~(size_t)255;
    return p;
  };
  unsigned short* wslot = (unsigned short*)alloc(5632ull * 2048 * 2);
  float* cosT           = (float*)alloc(2048ull * 32 * 4);
  float* sinT           = (float*)alloc(2048ull * 32 * 4);
  unsigned short* hbuf  = (unsigned short*)alloc(4096ull * 2048 * 2);
  char* arena           = alloc(4096ull * 1536 * 2 + 4096ull * 3072 * 2);
  float* kvf            = (float*)alloc(4096ull * 640 * 4);
  unsigned short* kvn   = (unsigned short*)alloc(4096ull * 512 * 2);
  unsigned short* Qc    = (unsigned short*)alloc(32ull * 2048 * 192 * 2);
  unsigned short* Kc    = (unsigned short*)alloc(32ull * 2048 * 192 * 2);
  unsigned short* VTb   = (unsigned short*)alloc(32ull * 128 * 2048 * 2);
  const size_t NEED = off;

  if (ws_size < NEED) {
    fill_k<<<dim3((out_size + 255) / 256), dim3(256), 0, stream>>>(
        out, (float)(ws_size >> 20), out_size);
    return;
  }

  unsigned short* qd    = (unsigned short*)arena;
  unsigned short* q     = (unsigned short*)(arena + 4096ull * 1536 * 2);
  unsigned short* kvex  = (unsigned short*)arena;
  unsigned short* h     = hbuf;
  unsigned short* attnb = hbuf;
  unsigned short* h2    = hbuf;
  unsigned short* gbuf  = Qc;
  float* x2             = out;

  dim3 blk(256), blk512(512);
  rope_tab<<<dim3(256), blk, 0, stream>>>(cosT, sinT);
  rmsnorm_k<<<dim3(4096), blk, 0, stream>>>(x, anw, h, 2048, 2048, 2048);

  // q path
  wtrans<<<dim3(24, 32), blk, 0, stream>>>(wqd, wslot, 2048, 1536);
  gemm_sb1<EPI_BF16><<<dim3(32 * 12), blk, 0, stream>>>(h, wslot, qd, nullptr, nullptr, 4096, 1536, 2048);
  wtrans<<<dim3(48, 24), blk, 0, stream>>>(wqu, wslot, 1536, 3072);
  gemm_sb1<EPI_BF16><<<dim3(32 * 24), blk, 0, stream>>>(qd, wslot, q, nullptr, nullptr, 4096, 3072, 1536);
  repack_q<<<dim3(4096), blk, 0, stream>>>(q, cosT, sinT, Qc);

  // kv path
  wtrans<<<dim3(9, 32), blk, 0, stream>>>(wkvd, wslot, 2048, 576);
  gemm_sb1<EPI_F32><<<dim3(32 * 5), blk, 0, stream>>>(h, wslot, kvf, nullptr, nullptr, 4096, 640, 2048);
  rmsnorm_k<<<dim3(4096), blk, 0, stream>>>(kvf, kvnw, kvn, 512, 640, 512);
  wtrans<<<dim3(64, 8), blk, 0, stream>>>(wkvu, wslot, 512, 4096);
  gemm_sb1<EPI_BF16><<<dim3(32 * 32), blk, 0, stream>>>(kvn, wslot, kvex, nullptr, nullptr, 4096, 4096, 512);
  repack_kv<<<dim3(2048), blk, 0, stream>>>(kvex, kvf, cosT, sinT, Kc, VTb);

  // attention
  attn_k<<<dim3(512), blk512, 0, stream>>>(Qc, Kc, VTb, attnb);
  wtrans<<<dim3(32, 32), blk, 0, stream>>>(wout, wslot, 2048, 2048);
  gemm_sb1<EPI_ADDF32><<<dim3(32 * 16), blk, 0, stream>>>(attnb, wslot, x2, x, nullptr, 4096, 2048, 2048);

  // ffn path — A/B: gate on sb3 (128x256), up on sb1 (EPI_SILU), down on sb1.
  rmsnorm_k<<<dim3(4096), blk, 0, stream>>>(x2, fnw, h2, 2048, 2048, 2048);
  wtrans<<<dim3(88, 32), blk, 0, stream>>>(wg, wslot, 2048, 5632);
  gemm_sb3<EPI_BF16><<<dim3(32 * 22), blk, 0, stream>>>(h2, wslot, gbuf, nullptr, nullptr, 4096, 5632, 2048);
  wtrans<<<dim3(88, 32), blk, 0, stream>>>(wu, wslot, 2048, 5632);
  gemm_sb1<EPI_SILU><<<dim3(32 * 44), blk, 0, stream>>>(h2, wslot, gbuf, nullptr, gbuf, 4096, 5632, 2048);
  wtrans<<<dim3(32, 88), blk, 0, stream>>>(wd, wslot, 5632, 2048);
  gemm_sb1<EPI_ADDF32><<<dim3(32 * 16), blk, 0, stream>>>(gbuf, wslot, out, x2, nullptr, 4096, 2048, 5632);
}

// Round 16
// 756.398 us; speedup vs baseline: 1.1542x; 1.1012x over previous
//
#include <hip/hip_runtime.h>
#include <hip/hip_bf16.h>

// MLA transformer block, bf16 MFMA implementation.
// R16: GEMMs = R11 config (sb1 everywhere; sb3/gu dead ends — VGPR/occupancy cliff).
//      Attention: single-buffer K (24KB) + dbuf V (32KB) + P (18KB) = 74KB LDS
//      -> 2 blocks/CU (was 98KB/1 block). K re-staged mid-tile after per-wave
//      lgkm0+barrier (sb1 recipe); softmax+PV covers K staging latency.

using bf16x8 = __attribute__((ext_vector_type(8))) short;
using f32x4  = __attribute__((ext_vector_type(4))) float;

#define GLOBAL_AS __attribute__((address_space(1)))
#define LDS_AS    __attribute__((address_space(3)))
#define MFMA16(a, b, c) __builtin_amdgcn_mfma_f32_16x16x32_bf16((a), (b), (c), 0, 0, 0)

static constexpr int Sc = 2048;

__device__ __forceinline__ void gload16(const void* g, void* l) {
  __builtin_amdgcn_global_load_lds((const GLOBAL_AS unsigned int*)g,
                                   (LDS_AS unsigned int*)l, 16, 0, 0);
}
__device__ __forceinline__ float bf2f(unsigned short u) {
  union { float f; unsigned int i; } x; x.i = ((unsigned int)u) << 16; return x.f;
}
__device__ __forceinline__ unsigned short f2bf(float f) {
  union { float f; unsigned int i; } x; x.f = f;
  unsigned int i = x.i;
  return (unsigned short)((i + 0x7fffu + ((i >> 16) & 1u)) >> 16);
}
__device__ __forceinline__ int swz4(int r) { return ((r >> 2) & 3) ^ (r & 3); }

// ---------------- diagnostic fill (ws too small beacon) ----------------
__global__ void fill_k(float* out, float v, int n) {
  int i = blockIdx.x * 256 + threadIdx.x;
  if (i < n) out[i] = v;
}

// -------- weight transpose+cast: W[K][N] f32 -> WT[N][K] bf16, 64n x 64k tiles ------
__global__ __launch_bounds__(256) void wtrans(const float* __restrict__ W,
                                              unsigned short* __restrict__ WT,
                                              int K, int N) {
  __shared__ float t[64][65];
  const int n0 = blockIdx.x * 64, k0 = blockIdx.y * 64;
  const int tx = threadIdx.x & 15, ty = threadIdx.x >> 4;  // tx: n-gran, ty: k row
#pragma unroll
  for (int i = 0; i < 4; ++i) {
    int k = k0 + ty + i * 16;
    const float4 v = *(const float4*)(W + (size_t)k * N + n0 + tx * 4);
    t[ty + i * 16][tx * 4 + 0] = v.x;
    t[ty + i * 16][tx * 4 + 1] = v.y;
    t[ty + i * 16][tx * 4 + 2] = v.z;
    t[ty + i * 16][tx * 4 + 3] = v.w;
  }
  __syncthreads();
  const int kx = threadIdx.x & 7, ny = threadIdx.x >> 3;  // kx: k-octet, ny 0..31
#pragma unroll
  for (int i = 0; i < 2; ++i) {
    int nl = ny + i * 32;
    unsigned short u[8];
#pragma unroll
    for (int j = 0; j < 8; ++j) u[j] = f2bf(t[kx * 8 + j][nl]);
    *(uint4*)(WT + (size_t)(n0 + nl) * K + k0 + kx * 8) = *(uint4*)u;
  }
}

// ---------------- rope tables ----------------
__global__ void rope_tab(float* __restrict__ cosT, float* __restrict__ sinT) {
  int i = blockIdx.x * 256 + threadIdx.x;
  if (i >= Sc * 32) return;
  int s = i >> 5, j = i & 31;
  float inv = powf(10000.0f, -(float)j / 32.0f);
  float a = (float)s * inv;
  cosT[i] = cosf(a);
  sinT[i] = sinf(a);
}

// ---------------- rmsnorm (f32 in, bf16 out) ----------------
__global__ __launch_bounds__(256) void rmsnorm_k(const float* __restrict__ in,
                                                 const float* __restrict__ w,
                                                 unsigned short* __restrict__ out,
                                                 int D, int istride, int ostride) {
  const int row = blockIdx.x;
  const float* x = in + (size_t)row * istride;
  float ss = 0.f;
  for (int c = threadIdx.x * 4; c < D; c += 1024) {
    const float4 v = *(const float4*)(x + c);
    ss += v.x * v.x + v.y * v.y + v.z * v.z + v.w * v.w;
  }
#pragma unroll
  for (int off = 1; off < 64; off <<= 1) ss += __shfl_xor(ss, off);
  __shared__ float part[4];
  if ((threadIdx.x & 63) == 0) part[threadIdx.x >> 6] = ss;
  __syncthreads();
  float tot = part[0] + part[1] + part[2] + part[3];
  float r = rsqrtf(tot / (float)D + 1e-6f);
  for (int c = threadIdx.x * 4; c < D; c += 1024) {
    const float4 v = *(const float4*)(x + c);
    ushort4 o;
    o.x = f2bf(v.x * r * w[c + 0]);
    o.y = f2bf(v.y * r * w[c + 1]);
    o.z = f2bf(v.z * r * w[c + 2]);
    o.w = f2bf(v.w * r * w[c + 3]);
    *(ushort4*)(out + (size_t)row * ostride + c) = o;
  }
}

enum { EPI_BF16 = 0, EPI_F32 = 1, EPI_ADDF32 = 2, EPI_SILU = 3 };

// ===== gemm_sb1: 128x128, BK=64, 4 waves, SINGLE-buffer LDS (32 KB) — R11 split ====
template <int EPI>
__global__ __launch_bounds__(256) void gemm_sb1(const unsigned short* __restrict__ A,
                                                const unsigned short* __restrict__ BT,
                                                void* __restrict__ Cp,
                                                const float* __restrict__ resid,
                                                const unsigned short* __restrict__ other,
                                                int M, int N, int K) {
  __shared__ unsigned short ldsA[128 * 64];
  __shared__ unsigned short ldsB[128 * 64];
  const int tid = threadIdx.x;
  const int w = tid >> 6, lane = tid & 63;
  const int rl = lane & 15, gh = lane >> 4;
  const int wm = (w >> 1) * 64, wn = (w & 1) * 64;

  const int nwg = gridDim.x;
  const int orig = blockIdx.x;
  const int qq = nwg >> 3, rr = nwg & 7;
  const int xcd = orig & 7, lidx = orig >> 3;
  const int fswz = (xcd < rr ? xcd * (qq + 1) : rr * (qq + 1) + (xcd - rr) * qq) + lidx;
  const int MT = M >> 7;
  const int m0 = (fswz % MT) * 128;
  const int n0 = (fswz / MT) * 128;

  const unsigned short* sA[4];
  const unsigned short* sB[4];
#pragma unroll
  for (int i = 0; i < 4; ++i) {
    int G = i * 256 + tid, r = G >> 3, sl = (G & 7) ^ (r & 7);
    sA[i] = A + (size_t)(m0 + r) * K + sl * 8;
    sB[i] = BT + (size_t)(n0 + r) * K + sl * 8;
  }
  auto STAGE = [&](int kt) {
    const int ko = kt * 64;
#pragma unroll
    for (int i = 0; i < 4; ++i) {
      gload16(sA[i] + ko, &ldsA[(i * 256 + w * 64) * 8]);
      gload16(sB[i] + ko, &ldsB[(i * 256 + w * 64) * 8]);
    }
  };

  int aoff[4], boff[4];
#pragma unroll
  for (int i = 0; i < 4; ++i) {
    aoff[i] = (wm + i * 16 + rl) * 64;
    boff[i] = (wn + i * 16 + rl) * 64;
  }

  f32x4 acc[4][4] = {};
  const int nk = K >> 6;

  STAGE(0);
  asm volatile("s_waitcnt vmcnt(0)" ::: "memory");
  __builtin_amdgcn_s_barrier();

  for (int kt = 0; kt < nk; ++kt) {
    bf16x8 a[4][2], b[4][2];
#pragma unroll
    for (int i = 0; i < 4; ++i)
#pragma unroll
      for (int ks = 0; ks < 2; ++ks) {
        const int ra = wm + i * 16 + rl;
        a[i][ks] = *(const bf16x8*)&ldsA[aoff[i] + ((((ks << 2) + gh)) ^ (ra & 7)) * 8];
        const int rb = wn + i * 16 + rl;
        b[i][ks] = *(const bf16x8*)&ldsB[boff[i] + ((((ks << 2) + gh)) ^ (rb & 7)) * 8];
      }
    asm volatile("s_waitcnt lgkmcnt(0)" ::: "memory");
    __builtin_amdgcn_sched_barrier(0);
    __builtin_amdgcn_s_setprio(1);
#pragma unroll
    for (int i = 0; i < 4; ++i)
#pragma unroll
      for (int j = 0; j < 4; ++j) acc[i][j] = MFMA16(a[i][0], b[j][0], acc[i][j]);
    __builtin_amdgcn_s_setprio(0);
    __builtin_amdgcn_sched_barrier(0);
    __builtin_amdgcn_s_barrier();
    STAGE((kt + 1 < nk) ? kt + 1 : nk - 1);
    __builtin_amdgcn_sched_barrier(0);
    __builtin_amdgcn_s_setprio(1);
#pragma unroll
    for (int i = 0; i < 4; ++i)
#pragma unroll
      for (int j = 0; j < 4; ++j) acc[i][j] = MFMA16(a[i][1], b[j][1], acc[i][j]);
    __builtin_amdgcn_s_setprio(0);
    __builtin_amdgcn_sched_barrier(0);
    asm volatile("s_waitcnt vmcnt(0)" ::: "memory");
    __builtin_amdgcn_s_barrier();
  }

#pragma unroll
  for (int i = 0; i < 4; ++i) {
#pragma unroll
    for (int j = 0; j < 4; ++j) {
#pragma unroll
      for (int rg = 0; rg < 4; ++rg) {
        const int row = m0 + wm + i * 16 + gh * 4 + rg;
        const int col = n0 + wn + j * 16 + rl;
        const size_t idx = (size_t)row * N + col;
        const float v = acc[i][j][rg];
        if constexpr (EPI == EPI_BF16) {
          ((unsigned short*)Cp)[idx] = f2bf(v);
        } else if constexpr (EPI == EPI_F32) {
          ((float*)Cp)[idx] = v;
        } else if constexpr (EPI == EPI_ADDF32) {
          ((float*)Cp)[idx] = v + resid[idx];
        } else {
          float gv = bf2f(other[idx]);
          float sg = gv / (1.f + __expf(-gv));
          ((unsigned short*)Cp)[idx] = f2bf(sg * v);
        }
      }
    }
  }
}

// ---------------- q repack: [B*S][NH*192] bf16 -> Qc[b,h,s,192] (rope + scale) -------
__global__ __launch_bounds__(256) void repack_q(const unsigned short* __restrict__ q,
                                                const float* __restrict__ cosT,
                                                const float* __restrict__ sinT,
                                                unsigned short* __restrict__ Qc) {
  const int row = blockIdx.x;  // b*S + s
  const int b = row >> 11, s = row & 2047;
  const float scale = 0.07216878364870322f;  // 1/sqrt(192)
  const unsigned short* qr = q + (size_t)row * 3072;
  for (int i = threadIdx.x; i < 3072; i += 256) {
    int h = i / 192, d = i - h * 192;
    float v;
    if (d < 128) {
      v = bf2f(qr[h * 192 + d]);
    } else {
      int j = d - 128;
      int jj = j & 31;
      float x1 = bf2f(qr[h * 192 + 128 + jj]);
      float x2 = bf2f(qr[h * 192 + 160 + jj]);
      float c = cosT[s * 32 + jj], sn = sinT[s * 32 + jj];
      v = (j < 32) ? (x1 * c - x2 * sn) : (x2 * c + x1 * sn);
    }
    Qc[((size_t)(b * 16 + h) * Sc + s) * 192 + d] = f2bf(v * scale);
  }
}

// ------- kv repack: build Kc[b,h,s,192] (nope | roped k_rope) and VT[b,h,f,s] -------
__global__ __launch_bounds__(256) void repack_kv(const unsigned short* __restrict__ kvex,
                                                 const float* __restrict__ kvf,
                                                 const float* __restrict__ cosT,
                                                 const float* __restrict__ sinT,
                                                 unsigned short* __restrict__ Kc,
                                                 unsigned short* __restrict__ VT) {
  __shared__ unsigned short vt_lds[32][136];
  const int bid = blockIdx.x;
  const int st = bid & 63;
  const int h = (bid >> 6) & 15;
  const int b = bid >> 10;
  const int s0 = st * 32;
  const int tid = threadIdx.x;
  const size_t KcBase = (size_t)(b * 16 + h) * Sc;
  for (int i = tid; i < 32 * 32; i += 256) {
    int r = i >> 5, g = i & 31;
    uint4 vdat = *(const uint4*)(kvex + (size_t)(b * Sc + s0 + r) * 4096 + h * 256 + g * 8);
    if (g < 16) {
      *(uint4*)(Kc + (KcBase + s0 + r) * 192 + g * 8) = vdat;
    } else {
      *(uint4*)(&vt_lds[r][(g - 16) * 8]) = vdat;
    }
  }
  for (int i = tid; i < 32 * 64; i += 256) {
    int r = i >> 6, d = i & 63;
    int s = s0 + r;
    int jj = d & 31;
    const float* kvrow = kvf + (size_t)(b * Sc + s) * 640;
    float x1 = kvrow[512 + jj], x2 = kvrow[544 + jj];
    float c = cosT[s * 32 + jj], sn = sinT[s * 32 + jj];
    float v = (d < 32) ? (x1 * c - x2 * sn) : (x2 * c + x1 * sn);
    Kc[(KcBase + s) * 192 + 128 + d] = f2bf(v);
  }
  __syncthreads();
  const int f = tid >> 1, sh = (tid & 1) * 16;
  unsigned int vals[8];
#pragma unroll
  for (int k2 = 0; k2 < 8; ++k2) {
    unsigned int lo = vt_lds[sh + 2 * k2][f];
    unsigned int hi = vt_lds[sh + 2 * k2 + 1][f];
    vals[k2] = lo | (hi << 16);
  }
  unsigned short* dst = VT + ((size_t)(b * 16 + h) * 128 + f) * Sc + s0 + sh;
  ((uint4*)dst)[0] = make_uint4(vals[0], vals[1], vals[2], vals[3]);
  ((uint4*)dst)[1] = make_uint4(vals[4], vals[5], vals[6], vals[7]);
}

// -------- flash attention: 8 waves, q-tile 128, KVBLK 64, single-K + dbuf-V --------
// LDS 74 KB -> 2 blocks/CU. Per tile: QK(reads+MFMA) -> lgkm0 -> barrier ->
// STAGE_K(t+1) -> softmax+PV (covers K latency) -> vmcnt0 -> barrier.
__global__ __launch_bounds__(512) void attn_k(const unsigned short* __restrict__ Qc,
                                              const unsigned short* __restrict__ Kc,
                                              const unsigned short* __restrict__ VT,
                                              unsigned short* __restrict__ Ob) {
  __shared__ unsigned short lds_k[64 * 192];          // 24 KB single-buffer
  __shared__ unsigned short lds_v[2][128 * 64];       // 32 KB dbuf
  __shared__ __align__(16) unsigned short p_lds[8][16 * 72];  // 18 KB
  const int tid = threadIdx.x, w = tid >> 6, lane = tid & 63;
  const int rl = lane & 15, gh = lane >> 4;
  const int bidx = blockIdx.x;
  const int bh = bidx & 31;
  const int qt = 15 - (bidx >> 5);   // longest q-tiles dispatch first
  const unsigned short* Qh = Qc + (size_t)bh * Sc * 192;
  const unsigned short* Kh = Kc + (size_t)bh * Sc * 192;
  const unsigned short* Vh = VT + (size_t)bh * 128 * Sc;
  const int qr0 = qt * 128 + w * 16;

  bf16x8 qf[6];
#pragma unroll
  for (int kk = 0; kk < 6; ++kk)
    qf[kk] = *(const bf16x8*)(Qh + (size_t)(qr0 + rl) * 192 + kk * 32 + gh * 8);

  f32x4 o[8] = {};
  float mrun[4] = {-1e30f, -1e30f, -1e30f, -1e30f};
  float srun[4] = {0.f, 0.f, 0.f, 0.f};

  int kr[3], kg[3];
#pragma unroll
  for (int j = 0; j < 3; ++j) {
    int G = j * 512 + tid;
    int r = G / 24, gq = G - r * 24;
    kr[j] = r;
    kg[j] = (gq & ~7) | ((gq & 7) ^ (r & 7));
  }
  int vr[2], vg[2];
#pragma unroll
  for (int j = 0; j < 2; ++j) {
    int G = j * 512 + tid;
    int r = G >> 3;
    vr[j] = r;
    vg[j] = (G & 7) ^ (r & 7);
  }

  auto STAGE_K = [&](int t) {
    const int k0 = t * 64;
#pragma unroll
    for (int j = 0; j < 3; ++j)
      gload16(Kh + (size_t)(k0 + kr[j]) * 192 + kg[j] * 8,
              &lds_k[(j * 512 + w * 64) * 8]);
  };
  auto STAGE_V = [&](int t, int b) {
    const int k0 = t * 64;
#pragma unroll
    for (int j = 0; j < 2; ++j)
      gload16(Vh + (size_t)vr[j] * Sc + k0 + vg[j] * 8,
              &lds_v[b][(j * 512 + w * 64) * 8]);
  };

  STAGE_K(0);
  STAGE_V(0, 0);
  asm volatile("s_waitcnt vmcnt(0)" ::: "memory");
  __builtin_amdgcn_s_barrier();
  __builtin_amdgcn_sched_barrier(0);

  const int nt = 2 * qt + 2;
  int vcur = 0;
  for (int t = 0; t < nt; ++t) {
    if (t + 1 < nt) STAGE_V(t + 1, vcur ^ 1);  // V prefetch (latency hides under tile)
    const int k0 = t * 64;
    const bool docomp = (k0 <= qr0 + 15);
    f32x4 s[4] = {};
    if (docomp) {
      // QK: reads+MFMA compiler-interleaved from single K buffer
      __builtin_amdgcn_s_setprio(1);
#pragma unroll
      for (int kk = 0; kk < 6; ++kk) {
        const int gq = kk * 4 + gh;
#pragma unroll
        for (int ks = 0; ks < 4; ++ks) {
          const int krow = ks * 16 + rl;
          const int ph = (gq & ~7) | ((gq & 7) ^ (krow & 7));
          bf16x8 kf = *(const bf16x8*)&lds_k[krow * 192 + ph * 8];
          s[ks] = MFMA16(qf[kk], kf, s[ks]);
        }
      }
      __builtin_amdgcn_s_setprio(0);
      asm volatile("s_waitcnt lgkmcnt(0)" ::: "memory");  // my K reads drained
    }
    __builtin_amdgcn_sched_barrier(0);
    __builtin_amdgcn_s_barrier();            // all waves' K reads done -> K buf free
    if (t + 1 < nt) STAGE_K(t + 1);          // overwrite K buffer; softmax+PV covers
    __builtin_amdgcn_sched_barrier(0);
    if (docomp) {
      if (k0 + 63 > qr0) {  // causal mask at boundary
#pragma unroll
        for (int ks = 0; ks < 4; ++ks)
#pragma unroll
          for (int rg = 0; rg < 4; ++rg) {
            int qrow = qr0 + gh * 4 + rg;
            if (k0 + ks * 16 + rl > qrow) s[ks][rg] = -1e30f;
          }
      }
      float tmax[4];
#pragma unroll
      for (int rg = 0; rg < 4; ++rg) {
        float v = fmaxf(fmaxf(s[0][rg], s[1][rg]), fmaxf(s[2][rg], s[3][rg]));
        v = fmaxf(v, __shfl_xor(v, 1));
        v = fmaxf(v, __shfl_xor(v, 2));
        v = fmaxf(v, __shfl_xor(v, 4));
        v = fmaxf(v, __shfl_xor(v, 8));
        tmax[rg] = v;
      }
      int need = !(tmax[0] <= mrun[0] + 8.f && tmax[1] <= mrun[1] + 8.f &&
                   tmax[2] <= mrun[2] + 8.f && tmax[3] <= mrun[3] + 8.f);
      if (__any(need)) {
        float al[4];
#pragma unroll
        for (int rg = 0; rg < 4; ++rg) {
          float mn = fmaxf(mrun[rg], tmax[rg]);
          al[rg] = __expf(mrun[rg] - mn);
          mrun[rg] = mn;
          srun[rg] *= al[rg];
        }
#pragma unroll
        for (int i = 0; i < 8; ++i)
#pragma unroll
          for (int rg = 0; rg < 4; ++rg) o[i][rg] *= al[rg];
      }
      unsigned short* pw = p_lds[w];
#pragma unroll
      for (int ks = 0; ks < 4; ++ks)
#pragma unroll
        for (int rg = 0; rg < 4; ++rg) {
          float p = __expf(s[ks][rg] - mrun[rg]);
          srun[rg] += p;
          pw[(gh * 4 + rg) * 72 + ks * 16 + rl] = f2bf(p);
        }
      bf16x8 pa0 = *(const bf16x8*)&pw[rl * 72 + 0 * 32 + gh * 8];
      bf16x8 pa1 = *(const bf16x8*)&pw[rl * 72 + 1 * 32 + gh * 8];
      const unsigned short* lv = lds_v[vcur];
      __builtin_amdgcn_s_setprio(1);
#pragma unroll
      for (int vf = 0; vf < 8; ++vf) {
        const int row = vf * 16 + rl;
        bf16x8 v0 = *(const bf16x8*)&lv[row * 64 + ((0 * 4 + gh) ^ (row & 7)) * 8];
        o[vf] = MFMA16(pa0, v0, o[vf]);
        bf16x8 v1 = *(const bf16x8*)&lv[row * 64 + ((1 * 4 + gh) ^ (row & 7)) * 8];
        o[vf] = MFMA16(pa1, v1, o[vf]);
      }
      __builtin_amdgcn_s_setprio(0);
    }
    asm volatile("s_waitcnt vmcnt(0)" ::: "memory");  // K(t+1), V(t+1) landed
    __builtin_amdgcn_s_barrier();
    __builtin_amdgcn_sched_barrier(0);
    vcur ^= 1;
  }
  float rd[4];
#pragma unroll
  for (int rg = 0; rg < 4; ++rg) {
    float rs = srun[rg];
    rs += __shfl_xor(rs, 1);
    rs += __shfl_xor(rs, 2);
    rs += __shfl_xor(rs, 4);
    rs += __shfl_xor(rs, 8);
    rd[rg] = 1.f / rs;
  }
  const int b = bh >> 4, hh = bh & 15;
#pragma unroll
  for (int vf = 0; vf < 8; ++vf) {
#pragma unroll
    for (int rg = 0; rg < 4; ++rg) {
      int srow = qr0 + gh * 4 + rg;
      int col = hh * 128 + vf * 16 + rl;
      Ob[((size_t)(b * Sc) + srow) * 2048 + col] = f2bf(o[vf][rg] * rd[rg]);
    }
  }
}

// ---------------- host ----------------
extern "C" void kernel_launch(void* const* d_in, const int* in_sizes, int n_in,
                              void* d_out, int out_size, void* d_ws, size_t ws_size,
                              hipStream_t stream) {
  (void)in_sizes; (void)n_in;
  const float* x    = (const float*)d_in[0];
  const float* anw  = (const float*)d_in[1];
  const float* wqd  = (const float*)d_in[2];
  const float* wqu  = (const float*)d_in[3];
  const float* wkvd = (const float*)d_in[4];
  const float* kvnw = (const float*)d_in[5];
  const float* wkvu = (const float*)d_in[6];
  const float* wout = (const float*)d_in[7];
  const float* fnw  = (const float*)d_in[8];
  const float* wg   = (const float*)d_in[9];
  const float* wu   = (const float*)d_in[10];
  const float* wd   = (const float*)d_in[11];
  float* out = (float*)d_out;

  char* ws = (char*)d_ws;
  size_t off = 0;
  auto alloc = [&](size_t bytes) -> char* {
    char* p = ws + off;
    off += (bytes + 255) & ~(size_t)255;
    return p;
  };
  unsigned short* wslot = (unsigned short*)alloc(5632ull * 2048 * 2);
  float* cosT           = (float*)alloc(2048ull * 32 * 4);
  float* sinT           = (float*)alloc(2048ull * 32 * 4);
  unsigned short* hbuf  = (unsigned short*)alloc(4096ull * 2048 * 2);
  char* arena           = alloc(4096ull * 1536 * 2 + 4096ull * 3072 * 2);
  float* kvf            = (float*)alloc(4096ull * 640 * 4);
  unsigned short* kvn   = (unsigned short*)alloc(4096ull * 512 * 2);
  unsigned short* Qc    = (unsigned short*)alloc(32ull * 2048 * 192 * 2);
  unsigned short* Kc    = (unsigned short*)alloc(32ull * 2048 * 192 * 2);
  unsigned short* VTb   = (unsigned short*)alloc(32ull * 128 * 2048 * 2);
  const size_t NEED = off;

  if (ws_size < NEED) {
    fill_k<<<dim3((out_size + 255) / 256), dim3(256), 0, stream>>>(
        out, (float)(ws_size >> 20), out_size);
    return;
  }

  unsigned short* qd    = (unsigned short*)arena;
  unsigned short* q     = (unsigned short*)(arena + 4096ull * 1536 * 2);
  unsigned short* kvex  = (unsigned short*)arena;
  unsigned short* h     = hbuf;
  unsigned short* attnb = hbuf;
  unsigned short* h2    = hbuf;
  unsigned short* gbuf  = Qc;
  float* x2             = out;

  dim3 blk(256), blk512(512);
  rope_tab<<<dim3(256), blk, 0, stream>>>(cosT, sinT);
  rmsnorm_k<<<dim3(4096), blk, 0, stream>>>(x, anw, h, 2048, 2048, 2048);

  // q path
  wtrans<<<dim3(24, 32), blk, 0, stream>>>(wqd, wslot, 2048, 1536);
  gemm_sb1<EPI_BF16><<<dim3(32 * 12), blk, 0, stream>>>(h, wslot, qd, nullptr, nullptr, 4096, 1536, 2048);
  wtrans<<<dim3(48, 24), blk, 0, stream>>>(wqu, wslot, 1536, 3072);
  gemm_sb1<EPI_BF16><<<dim3(32 * 24), blk, 0, stream>>>(qd, wslot, q, nullptr, nullptr, 4096, 3072, 1536);
  repack_q<<<dim3(4096), blk, 0, stream>>>(q, cosT, sinT, Qc);

  // kv path
  wtrans<<<dim3(9, 32), blk, 0, stream>>>(wkvd, wslot, 2048, 576);
  gemm_sb1<EPI_F32><<<dim3(32 * 5), blk, 0, stream>>>(h, wslot, kvf, nullptr, nullptr, 4096, 640, 2048);
  rmsnorm_k<<<dim3(4096), blk, 0, stream>>>(kvf, kvnw, kvn, 512, 640, 512);
  wtrans<<<dim3(64, 8), blk, 0, stream>>>(wkvu, wslot, 512, 4096);
  gemm_sb1<EPI_BF16><<<dim3(32 * 32), blk, 0, stream>>>(kvn, wslot, kvex, nullptr, nullptr, 4096, 4096, 512);
  repack_kv<<<dim3(2048), blk, 0, stream>>>(kvex, kvf, cosT, sinT, Kc, VTb);

  // attention
  attn_k<<<dim3(512), blk512, 0, stream>>>(Qc, Kc, VTb, attnb);
  wtrans<<<dim3(32, 32), blk, 0, stream>>>(wout, wslot, 2048, 2048);
  gemm_sb1<EPI_ADDF32><<<dim3(32 * 16), blk, 0, stream>>>(attnb, wslot, x2, x, nullptr, 4096, 2048, 2048);

  // ffn path (R11 config: sb1 gate, sb1 up+silu, sb1 down)
  rmsnorm_k<<<dim3(4096), blk, 0, stream>>>(x2, fnw, h2, 2048, 2048, 2048);
  wtrans<<<dim3(88, 32), blk, 0, stream>>>(wg, wslot, 2048, 5632);
  gemm_sb1<EPI_BF16><<<dim3(32 * 44), blk, 0, stream>>>(h2, wslot, gbuf, nullptr, nullptr, 4096, 5632, 2048);
  wtrans<<<dim3(88, 32), blk, 0, stream>>>(wu, wslot, 2048, 5632);
  gemm_sb1<EPI_SILU><<<dim3(32 * 44), blk, 0, stream>>>(h2, wslot, gbuf, nullptr, gbuf, 4096, 5632, 2048);
  wtrans<<<dim3(32, 88), blk, 0, stream>>>(wd, wslot, 5632, 2048);
  gemm_sb1<EPI_ADDF32><<<dim3(32 * 16), blk, 0, stream>>>(gbuf, wslot, out, x2, nullptr, 4096, 2048, 5632);
}

// Round 17
// 754.953 us; speedup vs baseline: 1.1564x; 1.0019x over previous
//
#include <hip/hip_runtime.h>
#include <hip/hip_bf16.h>

// MLA transformer block, bf16 MFMA implementation.
// R17: A/B on gate — gemm_sb1h: asymmetric 1.5-stage (dbuf B staged at loop TOP
//      with full-iter lead for HBM latency; single-buffer A staged mid-iter, L2-class
//      latency). 48KB LDS -> 3 blocks/CU. up stays sb1. Rest identical to R16 (756us).

using bf16x8 = __attribute__((ext_vector_type(8))) short;
using f32x4  = __attribute__((ext_vector_type(4))) float;

#define GLOBAL_AS __attribute__((address_space(1)))
#define LDS_AS    __attribute__((address_space(3)))
#define MFMA16(a, b, c) __builtin_amdgcn_mfma_f32_16x16x32_bf16((a), (b), (c), 0, 0, 0)

static constexpr int Sc = 2048;

__device__ __forceinline__ void gload16(const void* g, void* l) {
  __builtin_amdgcn_global_load_lds((const GLOBAL_AS unsigned int*)g,
                                   (LDS_AS unsigned int*)l, 16, 0, 0);
}
__device__ __forceinline__ float bf2f(unsigned short u) {
  union { float f; unsigned int i; } x; x.i = ((unsigned int)u) << 16; return x.f;
}
__device__ __forceinline__ unsigned short f2bf(float f) {
  union { float f; unsigned int i; } x; x.f = f;
  unsigned int i = x.i;
  return (unsigned short)((i + 0x7fffu + ((i >> 16) & 1u)) >> 16);
}
__device__ __forceinline__ int swz4(int r) { return ((r >> 2) & 3) ^ (r & 3); }

// ---------------- diagnostic fill (ws too small beacon) ----------------
__global__ void fill_k(float* out, float v, int n) {
  int i = blockIdx.x * 256 + threadIdx.x;
  if (i < n) out[i] = v;
}

// -------- weight transpose+cast: W[K][N] f32 -> WT[N][K] bf16, 64n x 64k tiles ------
__global__ __launch_bounds__(256) void wtrans(const float* __restrict__ W,
                                              unsigned short* __restrict__ WT,
                                              int K, int N) {
  __shared__ float t[64][65];
  const int n0 = blockIdx.x * 64, k0 = blockIdx.y * 64;
  const int tx = threadIdx.x & 15, ty = threadIdx.x >> 4;  // tx: n-gran, ty: k row
#pragma unroll
  for (int i = 0; i < 4; ++i) {
    int k = k0 + ty + i * 16;
    const float4 v = *(const float4*)(W + (size_t)k * N + n0 + tx * 4);
    t[ty + i * 16][tx * 4 + 0] = v.x;
    t[ty + i * 16][tx * 4 + 1] = v.y;
    t[ty + i * 16][tx * 4 + 2] = v.z;
    t[ty + i * 16][tx * 4 + 3] = v.w;
  }
  __syncthreads();
  const int kx = threadIdx.x & 7, ny = threadIdx.x >> 3;  // kx: k-octet, ny 0..31
#pragma unroll
  for (int i = 0; i < 2; ++i) {
    int nl = ny + i * 32;
    unsigned short u[8];
#pragma unroll
    for (int j = 0; j < 8; ++j) u[j] = f2bf(t[kx * 8 + j][nl]);
    *(uint4*)(WT + (size_t)(n0 + nl) * K + k0 + kx * 8) = *(uint4*)u;
  }
}

// ---------------- rope tables ----------------
__global__ void rope_tab(float* __restrict__ cosT, float* __restrict__ sinT) {
  int i = blockIdx.x * 256 + threadIdx.x;
  if (i >= Sc * 32) return;
  int s = i >> 5, j = i & 31;
  float inv = powf(10000.0f, -(float)j / 32.0f);
  float a = (float)s * inv;
  cosT[i] = cosf(a);
  sinT[i] = sinf(a);
}

// ---------------- rmsnorm (f32 in, bf16 out) ----------------
__global__ __launch_bounds__(256) void rmsnorm_k(const float* __restrict__ in,
                                                 const float* __restrict__ w,
                                                 unsigned short* __restrict__ out,
                                                 int D, int istride, int ostride) {
  const int row = blockIdx.x;
  const float* x = in + (size_t)row * istride;
  float ss = 0.f;
  for (int c = threadIdx.x * 4; c < D; c += 1024) {
    const float4 v = *(const float4*)(x + c);
    ss += v.x * v.x + v.y * v.y + v.z * v.z + v.w * v.w;
  }
#pragma unroll
  for (int off = 1; off < 64; off <<= 1) ss += __shfl_xor(ss, off);
  __shared__ float part[4];
  if ((threadIdx.x & 63) == 0) part[threadIdx.x >> 6] = ss;
  __syncthreads();
  float tot = part[0] + part[1] + part[2] + part[3];
  float r = rsqrtf(tot / (float)D + 1e-6f);
  for (int c = threadIdx.x * 4; c < D; c += 1024) {
    const float4 v = *(const float4*)(x + c);
    ushort4 o;
    o.x = f2bf(v.x * r * w[c + 0]);
    o.y = f2bf(v.y * r * w[c + 1]);
    o.z = f2bf(v.z * r * w[c + 2]);
    o.w = f2bf(v.w * r * w[c + 3]);
    *(ushort4*)(out + (size_t)row * ostride + c) = o;
  }
}

enum { EPI_BF16 = 0, EPI_F32 = 1, EPI_ADDF32 = 2, EPI_SILU = 3 };

// ===== gemm_sb1: 128x128, BK=64, 4 waves, SINGLE-buffer LDS (32 KB) — R11 split ====
template <int EPI>
__global__ __launch_bounds__(256) void gemm_sb1(const unsigned short* __restrict__ A,
                                                const unsigned short* __restrict__ BT,
                                                void* __restrict__ Cp,
                                                const float* __restrict__ resid,
                                                const unsigned short* __restrict__ other,
                                                int M, int N, int K) {
  __shared__ unsigned short ldsA[128 * 64];
  __shared__ unsigned short ldsB[128 * 64];
  const int tid = threadIdx.x;
  const int w = tid >> 6, lane = tid & 63;
  const int rl = lane & 15, gh = lane >> 4;
  const int wm = (w >> 1) * 64, wn = (w & 1) * 64;

  const int nwg = gridDim.x;
  const int orig = blockIdx.x;
  const int qq = nwg >> 3, rr = nwg & 7;
  const int xcd = orig & 7, lidx = orig >> 3;
  const int fswz = (xcd < rr ? xcd * (qq + 1) : rr * (qq + 1) + (xcd - rr) * qq) + lidx;
  const int MT = M >> 7;
  const int m0 = (fswz % MT) * 128;
  const int n0 = (fswz / MT) * 128;

  const unsigned short* sA[4];
  const unsigned short* sB[4];
#pragma unroll
  for (int i = 0; i < 4; ++i) {
    int G = i * 256 + tid, r = G >> 3, sl = (G & 7) ^ (r & 7);
    sA[i] = A + (size_t)(m0 + r) * K + sl * 8;
    sB[i] = BT + (size_t)(n0 + r) * K + sl * 8;
  }
  auto STAGE = [&](int kt) {
    const int ko = kt * 64;
#pragma unroll
    for (int i = 0; i < 4; ++i) {
      gload16(sA[i] + ko, &ldsA[(i * 256 + w * 64) * 8]);
      gload16(sB[i] + ko, &ldsB[(i * 256 + w * 64) * 8]);
    }
  };

  int aoff[4], boff[4];
#pragma unroll
  for (int i = 0; i < 4; ++i) {
    aoff[i] = (wm + i * 16 + rl) * 64;
    boff[i] = (wn + i * 16 + rl) * 64;
  }

  f32x4 acc[4][4] = {};
  const int nk = K >> 6;

  STAGE(0);
  asm volatile("s_waitcnt vmcnt(0)" ::: "memory");
  __builtin_amdgcn_s_barrier();

  for (int kt = 0; kt < nk; ++kt) {
    bf16x8 a[4][2], b[4][2];
#pragma unroll
    for (int i = 0; i < 4; ++i)
#pragma unroll
      for (int ks = 0; ks < 2; ++ks) {
        const int ra = wm + i * 16 + rl;
        a[i][ks] = *(const bf16x8*)&ldsA[aoff[i] + ((((ks << 2) + gh)) ^ (ra & 7)) * 8];
        const int rb = wn + i * 16 + rl;
        b[i][ks] = *(const bf16x8*)&ldsB[boff[i] + ((((ks << 2) + gh)) ^ (rb & 7)) * 8];
      }
    asm volatile("s_waitcnt lgkmcnt(0)" ::: "memory");
    __builtin_amdgcn_sched_barrier(0);
    __builtin_amdgcn_s_setprio(1);
#pragma unroll
    for (int i = 0; i < 4; ++i)
#pragma unroll
      for (int j = 0; j < 4; ++j) acc[i][j] = MFMA16(a[i][0], b[j][0], acc[i][j]);
    __builtin_amdgcn_s_setprio(0);
    __builtin_amdgcn_sched_barrier(0);
    __builtin_amdgcn_s_barrier();
    STAGE((kt + 1 < nk) ? kt + 1 : nk - 1);
    __builtin_amdgcn_sched_barrier(0);
    __builtin_amdgcn_s_setprio(1);
#pragma unroll
    for (int i = 0; i < 4; ++i)
#pragma unroll
      for (int j = 0; j < 4; ++j) acc[i][j] = MFMA16(a[i][1], b[j][1], acc[i][j]);
    __builtin_amdgcn_s_setprio(0);
    __builtin_amdgcn_sched_barrier(0);
    asm volatile("s_waitcnt vmcnt(0)" ::: "memory");
    __builtin_amdgcn_s_barrier();
  }

#pragma unroll
  for (int i = 0; i < 4; ++i) {
#pragma unroll
    for (int j = 0; j < 4; ++j) {
#pragma unroll
      for (int rg = 0; rg < 4; ++rg) {
        const int row = m0 + wm + i * 16 + gh * 4 + rg;
        const int col = n0 + wn + j * 16 + rl;
        const size_t idx = (size_t)row * N + col;
        const float v = acc[i][j][rg];
        if constexpr (EPI == EPI_BF16) {
          ((unsigned short*)Cp)[idx] = f2bf(v);
        } else if constexpr (EPI == EPI_F32) {
          ((float*)Cp)[idx] = v;
        } else if constexpr (EPI == EPI_ADDF32) {
          ((float*)Cp)[idx] = v + resid[idx];
        } else {
          float gv = bf2f(other[idx]);
          float sg = gv / (1.f + __expf(-gv));
          ((unsigned short*)Cp)[idx] = f2bf(sg * v);
        }
      }
    }
  }
}

// ===== gemm_sb1h: 128x128, BK=64, 4 waves, 1.5-stage (dbuf B + single A, 48 KB) ====
// STAGE_B(t+1) at loop TOP (full-iter HBM lead); STAGE_A(t+1) mid-iter (L2-class).
template <int EPI>
__global__ __launch_bounds__(256) void gemm_sb1h(const unsigned short* __restrict__ A,
                                                 const unsigned short* __restrict__ BT,
                                                 void* __restrict__ Cp,
                                                 const float* __restrict__ resid,
                                                 const unsigned short* __restrict__ other,
                                                 int M, int N, int K) {
  __shared__ unsigned short ldsA[128 * 64];        // 16 KB single
  __shared__ unsigned short ldsB[2][128 * 64];     // 32 KB dbuf
  const int tid = threadIdx.x;
  const int w = tid >> 6, lane = tid & 63;
  const int rl = lane & 15, gh = lane >> 4;
  const int wm = (w >> 1) * 64, wn = (w & 1) * 64;

  const int nwg = gridDim.x;
  const int orig = blockIdx.x;
  const int qq = nwg >> 3, rr = nwg & 7;
  const int xcd = orig & 7, lidx = orig >> 3;
  const int fswz = (xcd < rr ? xcd * (qq + 1) : rr * (qq + 1) + (xcd - rr) * qq) + lidx;
  const int MT = M >> 7;
  const int m0 = (fswz % MT) * 128;
  const int n0 = (fswz / MT) * 128;

  const unsigned short* sA[4];
  const unsigned short* sB[4];
#pragma unroll
  for (int i = 0; i < 4; ++i) {
    int G = i * 256 + tid, r = G >> 3, sl = (G & 7) ^ (r & 7);
    sA[i] = A + (size_t)(m0 + r) * K + sl * 8;
    sB[i] = BT + (size_t)(n0 + r) * K + sl * 8;
  }
  auto STAGE_A = [&](int kt) {
    const int ko = kt * 64;
#pragma unroll
    for (int i = 0; i < 4; ++i)
      gload16(sA[i] + ko, &ldsA[(i * 256 + w * 64) * 8]);
  };
  auto STAGE_B = [&](int kt, int p) {
    const int ko = kt * 64;
#pragma unroll
    for (int i = 0; i < 4; ++i)
      gload16(sB[i] + ko, &ldsB[p][(i * 256 + w * 64) * 8]);
  };

  int aoff[4], boff[4];
#pragma unroll
  for (int i = 0; i < 4; ++i) {
    aoff[i] = (wm + i * 16 + rl) * 64;
    boff[i] = (wn + i * 16 + rl) * 64;
  }

  f32x4 acc[4][4] = {};
  const int nk = K >> 6;

  STAGE_A(0);
  STAGE_B(0, 0);
  asm volatile("s_waitcnt vmcnt(0)" ::: "memory");
  __builtin_amdgcn_s_barrier();

  for (int kt = 0; kt < nk; ++kt) {
    const int bcur = kt & 1;
    // B(t+1) into the other buffer: its previous tile was consumed last iteration
    // (guaranteed by last iteration's lgkm0 + closing barrier). Full-iter HBM lead.
    STAGE_B((kt + 1 < nk) ? kt + 1 : nk - 1, bcur ^ 1);
    const unsigned short* lB = &ldsB[bcur][0];
    bf16x8 a[4][2], b[4][2];
#pragma unroll
    for (int i = 0; i < 4; ++i)
#pragma unroll
      for (int ks = 0; ks < 2; ++ks) {
        const int ra = wm + i * 16 + rl;
        a[i][ks] = *(const bf16x8*)&ldsA[aoff[i] + ((((ks << 2) + gh)) ^ (ra & 7)) * 8];
        const int rb = wn + i * 16 + rl;
        b[i][ks] = *(const bf16x8*)&lB[boff[i] + ((((ks << 2) + gh)) ^ (rb & 7)) * 8];
      }
    asm volatile("s_waitcnt lgkmcnt(0)" ::: "memory");  // my A + B[bcur] reads landed
    __builtin_amdgcn_sched_barrier(0);
    __builtin_amdgcn_s_setprio(1);
#pragma unroll
    for (int i = 0; i < 4; ++i)
#pragma unroll
      for (int j = 0; j < 4; ++j) acc[i][j] = MFMA16(a[i][0], b[j][0], acc[i][j]);
    __builtin_amdgcn_s_setprio(0);
    __builtin_amdgcn_sched_barrier(0);
    __builtin_amdgcn_s_barrier();                       // all waves done with A, B[bcur]
    STAGE_A((kt + 1 < nk) ? kt + 1 : nk - 1);           // overwrite A (L2-class latency)
    __builtin_amdgcn_sched_barrier(0);
    __builtin_amdgcn_s_setprio(1);
#pragma unroll
    for (int i = 0; i < 4; ++i)
#pragma unroll
      for (int j = 0; j < 4; ++j) acc[i][j] = MFMA16(a[i][1], b[j][1], acc[i][j]);
    __builtin_amdgcn_s_setprio(0);
    __builtin_amdgcn_sched_barrier(0);
    asm volatile("s_waitcnt vmcnt(0)" ::: "memory");    // A(t+1) + B(t+1) landed
    __builtin_amdgcn_s_barrier();
  }

#pragma unroll
  for (int i = 0; i < 4; ++i) {
#pragma unroll
    for (int j = 0; j < 4; ++j) {
#pragma unroll
      for (int rg = 0; rg < 4; ++rg) {
        const int row = m0 + wm + i * 16 + gh * 4 + rg;
        const int col = n0 + wn + j * 16 + rl;
        const size_t idx = (size_t)row * N + col;
        const float v = acc[i][j][rg];
        if constexpr (EPI == EPI_BF16) {
          ((unsigned short*)Cp)[idx] = f2bf(v);
        } else if constexpr (EPI == EPI_F32) {
          ((float*)Cp)[idx] = v;
        } else if constexpr (EPI == EPI_ADDF32) {
          ((float*)Cp)[idx] = v + resid[idx];
        } else {
          float gv = bf2f(other[idx]);
          float sg = gv / (1.f + __expf(-gv));
          ((unsigned short*)Cp)[idx] = f2bf(sg * v);
        }
      }
    }
  }
}

// ---------------- q repack: [B*S][NH*192] bf16 -> Qc[b,h,s,192] (rope + scale) -------
__global__ __launch_bounds__(256) void repack_q(const unsigned short* __restrict__ q,
                                                const float* __restrict__ cosT,
                                                const float* __restrict__ sinT,
                                                unsigned short* __restrict__ Qc) {
  const int row = blockIdx.x;  // b*S + s
  const int b = row >> 11, s = row & 2047;
  const float scale = 0.07216878364870322f;  // 1/sqrt(192)
  const unsigned short* qr = q + (size_t)row * 3072;
  for (int i = threadIdx.x; i < 3072; i += 256) {
    int h = i / 192, d = i - h * 192;
    float v;
    if (d < 128) {
      v = bf2f(qr[h * 192 + d]);
    } else {
      int j = d - 128;
      int jj = j & 31;
      float x1 = bf2f(qr[h * 192 + 128 + jj]);
      float x2 = bf2f(qr[h * 192 + 160 + jj]);
      float c = cosT[s * 32 + jj], sn = sinT[s * 32 + jj];
      v = (j < 32) ? (x1 * c - x2 * sn) : (x2 * c + x1 * sn);
    }
    Qc[((size_t)(b * 16 + h) * Sc + s) * 192 + d] = f2bf(v * scale);
  }
}

// ------- kv repack: build Kc[b,h,s,192] (nope | roped k_rope) and VT[b,h,f,s] -------
__global__ __launch_bounds__(256) void repack_kv(const unsigned short* __restrict__ kvex,
                                                 const float* __restrict__ kvf,
                                                 const float* __restrict__ cosT,
                                                 const float* __restrict__ sinT,
                                                 unsigned short* __restrict__ Kc,
                                                 unsigned short* __restrict__ VT) {
  __shared__ unsigned short vt_lds[32][136];
  const int bid = blockIdx.x;
  const int st = bid & 63;
  const int h = (bid >> 6) & 15;
  const int b = bid >> 10;
  const int s0 = st * 32;
  const int tid = threadIdx.x;
  const size_t KcBase = (size_t)(b * 16 + h) * Sc;
  for (int i = tid; i < 32 * 32; i += 256) {
    int r = i >> 5, g = i & 31;
    uint4 vdat = *(const uint4*)(kvex + (size_t)(b * Sc + s0 + r) * 4096 + h * 256 + g * 8);
    if (g < 16) {
      *(uint4*)(Kc + (KcBase + s0 + r) * 192 + g * 8) = vdat;
    } else {
      *(uint4*)(&vt_lds[r][(g - 16) * 8]) = vdat;
    }
  }
  for (int i = tid; i < 32 * 64; i += 256) {
    int r = i >> 6, d = i & 63;
    int s = s0 + r;
    int jj = d & 31;
    const float* kvrow = kvf + (size_t)(b * Sc + s) * 640;
    float x1 = kvrow[512 + jj], x2 = kvrow[544 + jj];
    float c = cosT[s * 32 + jj], sn = sinT[s * 32 + jj];
    float v = (d < 32) ? (x1 * c - x2 * sn) : (x2 * c + x1 * sn);
    Kc[(KcBase + s) * 192 + 128 + d] = f2bf(v);
  }
  __syncthreads();
  const int f = tid >> 1, sh = (tid & 1) * 16;
  unsigned int vals[8];
#pragma unroll
  for (int k2 = 0; k2 < 8; ++k2) {
    unsigned int lo = vt_lds[sh + 2 * k2][f];
    unsigned int hi = vt_lds[sh + 2 * k2 + 1][f];
    vals[k2] = lo | (hi << 16);
  }
  unsigned short* dst = VT + ((size_t)(b * 16 + h) * 128 + f) * Sc + s0 + sh;
  ((uint4*)dst)[0] = make_uint4(vals[0], vals[1], vals[2], vals[3]);
  ((uint4*)dst)[1] = make_uint4(vals[4], vals[5], vals[6], vals[7]);
}

// -------- flash attention: 8 waves, q-tile 128, KVBLK 64, single-K + dbuf-V --------
__global__ __launch_bounds__(512) void attn_k(const unsigned short* __restrict__ Qc,
                                              const unsigned short* __restrict__ Kc,
                                              const unsigned short* __restrict__ VT,
                                              unsigned short* __restrict__ Ob) {
  __shared__ unsigned short lds_k[64 * 192];
  __shared__ unsigned short lds_v[2][128 * 64];
  __shared__ __align__(16) unsigned short p_lds[8][16 * 72];
  const int tid = threadIdx.x, w = tid >> 6, lane = tid & 63;
  const int rl = lane & 15, gh = lane >> 4;
  const int bidx = blockIdx.x;
  const int bh = bidx & 31;
  const int qt = 15 - (bidx >> 5);
  const unsigned short* Qh = Qc + (size_t)bh * Sc * 192;
  const unsigned short* Kh = Kc + (size_t)bh * Sc * 192;
  const unsigned short* Vh = VT + (size_t)bh * 128 * Sc;
  const int qr0 = qt * 128 + w * 16;

  bf16x8 qf[6];
#pragma unroll
  for (int kk = 0; kk < 6; ++kk)
    qf[kk] = *(const bf16x8*)(Qh + (size_t)(qr0 + rl) * 192 + kk * 32 + gh * 8);

  f32x4 o[8] = {};
  float mrun[4] = {-1e30f, -1e30f, -1e30f, -1e30f};
  float srun[4] = {0.f, 0.f, 0.f, 0.f};

  int kr[3], kg[3];
#pragma unroll
  for (int j = 0; j < 3; ++j) {
    int G = j * 512 + tid;
    int r = G / 24, gq = G - r * 24;
    kr[j] = r;
    kg[j] = (gq & ~7) | ((gq & 7) ^ (r & 7));
  }
  int vr[2], vg[2];
#pragma unroll
  for (int j = 0; j < 2; ++j) {
    int G = j * 512 + tid;
    int r = G >> 3;
    vr[j] = r;
    vg[j] = (G & 7) ^ (r & 7);
  }

  auto STAGE_K = [&](int t) {
    const int k0 = t * 64;
#pragma unroll
    for (int j = 0; j < 3; ++j)
      gload16(Kh + (size_t)(k0 + kr[j]) * 192 + kg[j] * 8,
              &lds_k[(j * 512 + w * 64) * 8]);
  };
  auto STAGE_V = [&](int t, int b) {
    const int k0 = t * 64;
#pragma unroll
    for (int j = 0; j < 2; ++j)
      gload16(Vh + (size_t)vr[j] * Sc + k0 + vg[j] * 8,
              &lds_v[b][(j * 512 + w * 64) * 8]);
  };

  STAGE_K(0);
  STAGE_V(0, 0);
  asm volatile("s_waitcnt vmcnt(0)" ::: "memory");
  __builtin_amdgcn_s_barrier();
  __builtin_amdgcn_sched_barrier(0);

  const int nt = 2 * qt + 2;
  int vcur = 0;
  for (int t = 0; t < nt; ++t) {
    if (t + 1 < nt) STAGE_V(t + 1, vcur ^ 1);
    const int k0 = t * 64;
    const bool docomp = (k0 <= qr0 + 15);
    f32x4 s[4] = {};
    if (docomp) {
      __builtin_amdgcn_s_setprio(1);
#pragma unroll
      for (int kk = 0; kk < 6; ++kk) {
        const int gq = kk * 4 + gh;
#pragma unroll
        for (int ks = 0; ks < 4; ++ks) {
          const int krow = ks * 16 + rl;
          const int ph = (gq & ~7) | ((gq & 7) ^ (krow & 7));
          bf16x8 kf = *(const bf16x8*)&lds_k[krow * 192 + ph * 8];
          s[ks] = MFMA16(qf[kk], kf, s[ks]);
        }
      }
      __builtin_amdgcn_s_setprio(0);
      asm volatile("s_waitcnt lgkmcnt(0)" ::: "memory");
    }
    __builtin_amdgcn_sched_barrier(0);
    __builtin_amdgcn_s_barrier();
    if (t + 1 < nt) STAGE_K(t + 1);
    __builtin_amdgcn_sched_barrier(0);
    if (docomp) {
      if (k0 + 63 > qr0) {
#pragma unroll
        for (int ks = 0; ks < 4; ++ks)
#pragma unroll
          for (int rg = 0; rg < 4; ++rg) {
            int qrow = qr0 + gh * 4 + rg;
            if (k0 + ks * 16 + rl > qrow) s[ks][rg] = -1e30f;
          }
      }
      float tmax[4];
#pragma unroll
      for (int rg = 0; rg < 4; ++rg) {
        float v = fmaxf(fmaxf(s[0][rg], s[1][rg]), fmaxf(s[2][rg], s[3][rg]));
        v = fmaxf(v, __shfl_xor(v, 1));
        v = fmaxf(v, __shfl_xor(v, 2));
        v = fmaxf(v, __shfl_xor(v, 4));
        v = fmaxf(v, __shfl_xor(v, 8));
        tmax[rg] = v;
      }
      int need = !(tmax[0] <= mrun[0] + 8.f && tmax[1] <= mrun[1] + 8.f &&
                   tmax[2] <= mrun[2] + 8.f && tmax[3] <= mrun[3] + 8.f);
      if (__any(need)) {
        float al[4];
#pragma unroll
        for (int rg = 0; rg < 4; ++rg) {
          float mn = fmaxf(mrun[rg], tmax[rg]);
          al[rg] = __expf(mrun[rg] - mn);
          mrun[rg] = mn;
          srun[rg] *= al[rg];
        }
#pragma unroll
        for (int i = 0; i < 8; ++i)
#pragma unroll
          for (int rg = 0; rg < 4; ++rg) o[i][rg] *= al[rg];
      }
      unsigned short* pw = p_lds[w];
#pragma unroll
      for (int ks = 0; ks < 4; ++ks)
#pragma unroll
        for (int rg = 0; rg < 4; ++rg) {
          float p = __expf(s[ks][rg] - mrun[rg]);
          srun[rg] += p;
          pw[(gh * 4 + rg) * 72 + ks * 16 + rl] = f2bf(p);
        }
      bf16x8 pa0 = *(const bf16x8*)&pw[rl * 72 + 0 * 32 + gh * 8];
      bf16x8 pa1 = *(const bf16x8*)&pw[rl * 72 + 1 * 32 + gh * 8];
      const unsigned short* lv = lds_v[vcur];
      __builtin_amdgcn_s_setprio(1);
#pragma unroll
      for (int vf = 0; vf < 8; ++vf) {
        const int row = vf * 16 + rl;
        bf16x8 v0 = *(const bf16x8*)&lv[row * 64 + ((0 * 4 + gh) ^ (row & 7)) * 8];
        o[vf] = MFMA16(pa0, v0, o[vf]);
        bf16x8 v1 = *(const bf16x8*)&lv[row * 64 + ((1 * 4 + gh) ^ (row & 7)) * 8];
        o[vf] = MFMA16(pa1, v1, o[vf]);
      }
      __builtin_amdgcn_s_setprio(0);
    }
    asm volatile("s_waitcnt vmcnt(0)" ::: "memory");
    __builtin_amdgcn_s_barrier();
    __builtin_amdgcn_sched_barrier(0);
    vcur ^= 1;
  }
  float rd[4];
#pragma unroll
  for (int rg = 0; rg < 4; ++rg) {
    float rs = srun[rg];
    rs += __shfl_xor(rs, 1);
    rs += __shfl_xor(rs, 2);
    rs += __shfl_xor(rs, 4);
    rs += __shfl_xor(rs, 8);
    rd[rg] = 1.f / rs;
  }
  const int b = bh >> 4, hh = bh & 15;
#pragma unroll
  for (int vf = 0; vf < 8; ++vf) {
#pragma unroll
    for (int rg = 0; rg < 4; ++rg) {
      int srow = qr0 + gh * 4 + rg;
      int col = hh * 128 + vf * 16 + rl;
      Ob[((size_t)(b * Sc) + srow) * 2048 + col] = f2bf(o[vf][rg] * rd[rg]);
    }
  }
}

// ---------------- host ----------------
extern "C" void kernel_launch(void* const* d_in, const int* in_sizes, int n_in,
                              void* d_out, int out_size, void* d_ws, size_t ws_size,
                              hipStream_t stream) {
  (void)in_sizes; (void)n_in;
  const float* x    = (const float*)d_in[0];
  const float* anw  = (const float*)d_in[1];
  const float* wqd  = (const float*)d_in[2];
  const float* wqu  = (const float*)d_in[3];
  const float* wkvd = (const float*)d_in[4];
  const float* kvnw = (const float*)d_in[5];
  const float* wkvu = (const float*)d_in[6];
  const float* wout = (const float*)d_in[7];
  const float* fnw  = (const float*)d_in[8];
  const float* wg   = (const float*)d_in[9];
  const float* wu   = (const float*)d_in[10];
  const float* wd   = (const float*)d_in[11];
  float* out = (float*)d_out;

  char* ws = (char*)d_ws;
  size_t off = 0;
  auto alloc = [&](size_t bytes) -> char* {
    char* p = ws + off;
    off += (bytes + 255) & ~(size_t)255;
    return p;
  };
  unsigned short* wslot = (unsigned short*)alloc(5632ull * 2048 * 2);
  float* cosT           = (float*)alloc(2048ull * 32 * 4);
  float* sinT           = (float*)alloc(2048ull * 32 * 4);
  unsigned short* hbuf  = (unsigned short*)alloc(4096ull * 2048 * 2);
  char* arena           = alloc(4096ull * 1536 * 2 + 4096ull * 3072 * 2);
  float* kvf            = (float*)alloc(4096ull * 640 * 4);
  unsigned short* kvn   = (unsigned short*)alloc(4096ull * 512 * 2);
  unsigned short* Qc    = (unsigned short*)alloc(32ull * 2048 * 192 * 2);
  unsigned short* Kc    = (unsigned short*)alloc(32ull * 2048 * 192 * 2);
  unsigned short* VTb   = (unsigned short*)alloc(32ull * 128 * 2048 * 2);
  const size_t NEED = off;

  if (ws_size < NEED) {
    fill_k<<<dim3((out_size + 255) / 256), dim3(256), 0, stream>>>(
        out, (float)(ws_size >> 20), out_size);
    return;
  }

  unsigned short* qd    = (unsigned short*)arena;
  unsigned short* q     = (unsigned short*)(arena + 4096ull * 1536 * 2);
  unsigned short* kvex  = (unsigned short*)arena;
  unsigned short* h     = hbuf;
  unsigned short* attnb = hbuf;
  unsigned short* h2    = hbuf;
  unsigned short* gbuf  = Qc;
  float* x2             = out;

  dim3 blk(256), blk512(512);
  rope_tab<<<dim3(256), blk, 0, stream>>>(cosT, sinT);
  rmsnorm_k<<<dim3(4096), blk, 0, stream>>>(x, anw, h, 2048, 2048, 2048);

  // q path
  wtrans<<<dim3(24, 32), blk, 0, stream>>>(wqd, wslot, 2048, 1536);
  gemm_sb1<EPI_BF16><<<dim3(32 * 12), blk, 0, stream>>>(h, wslot, qd, nullptr, nullptr, 4096, 1536, 2048);
  wtrans<<<dim3(48, 24), blk, 0, stream>>>(wqu, wslot, 1536, 3072);
  gemm_sb1<EPI_BF16><<<dim3(32 * 24), blk, 0, stream>>>(qd, wslot, q, nullptr, nullptr, 4096, 3072, 1536);
  repack_q<<<dim3(4096), blk, 0, stream>>>(q, cosT, sinT, Qc);

  // kv path
  wtrans<<<dim3(9, 32), blk, 0, stream>>>(wkvd, wslot, 2048, 576);
  gemm_sb1<EPI_F32><<<dim3(32 * 5), blk, 0, stream>>>(h, wslot, kvf, nullptr, nullptr, 4096, 640, 2048);
  rmsnorm_k<<<dim3(4096), blk, 0, stream>>>(kvf, kvnw, kvn, 512, 640, 512);
  wtrans<<<dim3(64, 8), blk, 0, stream>>>(wkvu, wslot, 512, 4096);
  gemm_sb1<EPI_BF16><<<dim3(32 * 32), blk, 0, stream>>>(kvn, wslot, kvex, nullptr, nullptr, 4096, 4096, 512);
  repack_kv<<<dim3(2048), blk, 0, stream>>>(kvex, kvf, cosT, sinT, Kc, VTb);

  // attention
  attn_k<<<dim3(512), blk512, 0, stream>>>(Qc, Kc, VTb, attnb);
  wtrans<<<dim3(32, 32), blk, 0, stream>>>(wout, wslot, 2048, 2048);
  gemm_sb1<EPI_ADDF32><<<dim3(32 * 16), blk, 0, stream>>>(attnb, wslot, x2, x, nullptr, 4096, 2048, 2048);

  // ffn path — A/B: gate on sb1h (1.5-stage), up on sb1 (EPI_SILU), down on sb1.
  rmsnorm_k<<<dim3(4096), blk, 0, stream>>>(x2, fnw, h2, 2048, 2048, 2048);
  wtrans<<<dim3(88, 32), blk, 0, stream>>>(wg, wslot, 2048, 5632);
  gemm_sb1h<EPI_BF16><<<dim3(32 * 44), blk, 0, stream>>>(h2, wslot, gbuf, nullptr, nullptr, 4096, 5632, 2048);
  wtrans<<<dim3(88, 32), blk, 0, stream>>>(wu, wslot, 2048, 5632);
  gemm_sb1<EPI_SILU><<<dim3(32 * 44), blk, 0, stream>>>(h2, wslot, gbuf, nullptr, gbuf, 4096, 5632, 2048);
  wtrans<<<dim3(32, 88), blk, 0, stream>>>(wd, wslot, 5632, 2048);
  gemm_sb1<EPI_ADDF32><<<dim3(32 * 16), blk, 0, stream>>>(gbuf, wslot, out, x2, nullptr, 4096, 2048, 5632);
}